// Round 3
// baseline (3200.248 us; speedup 1.0000x reference)
//
#include <hip/hip_runtime.h>

#define BB 2
#define NN 20000
#define HH 128
#define EE 200000

typedef unsigned short u16;
typedef __attribute__((ext_vector_type(4))) float f32x4;
typedef __bf16 bf16x8 __attribute__((ext_vector_type(8)));

#define MFMA(a, b, c) __builtin_amdgcn_mfma_f32_16x16x32_bf16((a), (b), (c), 0, 0, 0)

__device__ __forceinline__ float bf2f(u16 u) {
    union { unsigned int i; float f; } v; v.i = ((unsigned int)u) << 16; return v.f;
}
__device__ __forceinline__ u16 f2bf(float f) {
    union { float f; unsigned int i; } v; v.f = f;
    unsigned int r = (v.i + 0x7FFFu + ((v.i >> 16) & 1u)) >> 16;
    return (u16)r;
}
// inputs are canonical bf16 -> z is bounded; fast exp silu is safe
__device__ __forceinline__ float silu_f(float z) { return z / (1.f + __expf(-z)); }

// packed bf16x2 atomic add (one 4B atomic covers 2 elements)
__device__ __forceinline__ void pk_add(u16* p, unsigned int v) {
#if __has_builtin(__builtin_amdgcn_global_atomic_fadd_v2bf16)
    typedef short s16x2 __attribute__((ext_vector_type(2)));
    union { unsigned int u; s16x2 s; } cv; cv.u = v;
    __builtin_amdgcn_global_atomic_fadd_v2bf16(
        (__attribute__((address_space(1))) s16x2*)(s16x2*)p, cv.s);
#else
    asm volatile("global_atomic_pk_add_bf16 %0, %1, off" :: "v"(p), "v"(v) : "memory");
#endif
}

// ---------------- dtype detection ----------------
__global__ void detect_kernel(const u16* __restrict__ f, int* __restrict__ flag) {
    int tid = threadIdx.x;
    u16 v = f[tid * 2];
    int e = (v >> 7) & 0xFF;
    int ok = (e >= 101 && e <= 143) ? 1 : 0;
    __shared__ int cnt;
    if (tid == 0) cnt = 0;
    __syncthreads();
    atomicAdd(&cnt, ok);
    __syncthreads();
    if (tid == 0) *flag = (cnt < 200) ? 1 : 0;   // 1 => inputs are float32
}

// ---------------- canonicalize all float inputs to bf16 in ws ----------------
#define CTOT 5461776
struct P24 { const void* p[24]; };

__global__ __launch_bounds__(256) void canon_kernel(P24 ptrs, const int* __restrict__ flag,
                                                    u16* __restrict__ canon) {
    static const int off[25] = {
        0, 5120000, 5240000, 5260000, 5280000, 5312896, 5313024, 5329408,
        5329536, 5345920, 5346048, 5346176, 5346184, 5379080, 5379208, 5395592,
        5395720, 5412104, 5412232, 5412360, 5412368, 5445136, 5445264, 5461648,
        5461776 };
    static const int rsz[24] = {
        5120000, 120000, 20000, 20000,
        32896, 128, 16384, 128, 16384, 128, 128, 1,
        32896, 128, 16384, 128, 16384, 128, 128, 1,
        32768, 128, 16384, 128 };
    int i = blockIdx.x * 256 + threadIdx.x;
    if (i >= CTOT) return;
    int t = 0;
#pragma unroll 1
    while (i >= off[t + 1]) ++t;
    int j = i - off[t];
    u16 v;
    if (j >= rsz[t]) v = 0;
    else if (*flag) v = f2bf(((const float*)ptrs.p[t])[j]);
    else v = ((const u16*)ptrs.p[t])[j];
    canon[i] = v;
}

// ---------------- weight fragment permutation ----------------
__global__ void make_frag(const u16* __restrict__ W, u16* __restrict__ F) {
    int tid = blockIdx.x * 256 + threadIdx.x;
    int j = tid & 7, lane = (tid >> 3) & 63, nt = (tid >> 9) & 7, kt = tid >> 12;
    int k = kt * 32 + ((lane >> 4) * 8) + j;
    int n = nt * 16 + (lane & 15);
    F[tid] = W[k * 128 + n];
}

// 2-LDS-buffer edge kernel: 36.6 KB LDS -> 4 blocks/CU
__global__ __launch_bounds__(256, 4) void edge_kernel(
    const u16* __restrict__ feat, const u16* __restrict__ posit,
    const int* __restrict__ eidx,
    const u16* __restrict__ fW1, const u16* __restrict__ w1last, const u16* __restrict__ bias1,
    const u16* __restrict__ fW2, const u16* __restrict__ bias2,
    const u16* __restrict__ fP1, const u16* __restrict__ biasp1,
    const u16* __restrict__ wp2, const u16* __restrict__ biasp2,
    u16* __restrict__ agg, float* __restrict__ pos_acc)
{
    const int tid = threadIdx.x;
    const int lane = tid & 63;
    const int wv = tid >> 6;
    const int row0 = blockIdx.x * 64;

    __shared__ u16 sX[64][136];   // h_src -> msg-hidden -> pos-hidden
    __shared__ u16 sY[64][136];   // h_dst -> messages
    __shared__ float sRel[64][3];
    __shared__ float sDist[64];
    __shared__ int sSrc[64], sDst[64], sBat[64];

    if (tid < 64) {
        int inst = row0 + tid;           // 0 .. B*E-1
        int b = inst / EE;
        int e = inst - b * EE;
        int s = eidx[e];
        int d = eidx[EE + e];
        sSrc[tid] = s; sDst[tid] = d; sBat[tid] = b;
        const u16* ps = posit + ((size_t)b * NN + s) * 3;
        const u16* pd = posit + ((size_t)b * NN + d) * 3;
        float dx = bf2f(ps[0]) - bf2f(pd[0]);
        float dy = bf2f(ps[1]) - bf2f(pd[1]);
        float dz = bf2f(ps[2]) - bf2f(pd[2]);
        sRel[tid][0] = dx; sRel[tid][1] = dy; sRel[tid][2] = dz;
        sDist[tid] = sqrtf(dx * dx + dy * dy + dz * dz);
    }
    __syncthreads();   // B0

    // gather h_src -> sX, h_dst -> sY
    {
        const int r = tid >> 2, part = tid & 3;
        const uint4* fs = (const uint4*)(feat + ((size_t)sBat[r] * NN + sSrc[r]) * HH);
        const uint4* fd = (const uint4*)(feat + ((size_t)sBat[r] * NN + sDst[r]) * HH);
        uint4* as = (uint4*)&sX[r][part * 32];
        uint4* ad = (uint4*)&sY[r][part * 32];
#pragma unroll
        for (int i = 0; i < 4; ++i) { as[i] = fs[part * 4 + i]; ad[i] = fd[part * 4 + i]; }
    }
    __syncthreads();   // B1

    const int nt0 = wv * 2;
    const int mrow = lane & 15;
    const int kq = (lane >> 4) * 8;
    const int crow = (lane >> 4) * 4;
    const int ccol = lane & 15;

    f32x4 acc[4][2];
#pragma unroll
    for (int mt = 0; mt < 4; ++mt) {
        acc[mt][0] = (f32x4){0.f, 0.f, 0.f, 0.f};
        acc[mt][1] = (f32x4){0.f, 0.f, 0.f, 0.f};
    }

    // ----- msg layer 1 : [h_src | h_dst] @ W1[0:256]  (K=256) -----
#pragma unroll
    for (int kt = 0; kt < 8; ++kt) {
        const u16* Xb = (kt < 4) ? &sX[0][0] : &sY[0][0];
        const int kk = (kt & 3) * 32 + kq;
        bf16x8 bw0 = *(const bf16x8*)(fW1 + (size_t)(((kt * 8 + nt0) * 64 + lane) * 8));
        bf16x8 bw1 = *(const bf16x8*)(fW1 + (size_t)(((kt * 8 + nt0 + 1) * 64 + lane) * 8));
#pragma unroll
        for (int mt = 0; mt < 4; ++mt) {
            bf16x8 a = *(const bf16x8*)(Xb + (mt * 16 + mrow) * 136 + kk);
            acc[mt][0] = MFMA(a, bw0, acc[mt][0]);
            acc[mt][1] = MFMA(a, bw1, acc[mt][1]);
        }
    }
    __syncthreads();   // B2: all L1 reads of sX/sY done

    // epilogue: + dist*W1[256] + b1, silu -> sX (overwrite h_src)
#pragma unroll
    for (int mt = 0; mt < 4; ++mt) {
#pragma unroll
        for (int n2 = 0; n2 < 2; ++n2) {
            const int col = (nt0 + n2) * 16 + ccol;
            const float wl = bf2f(w1last[col]);
            const float bb = bf2f(bias1[col]);
#pragma unroll
            for (int r = 0; r < 4; ++r) {
                const int row = mt * 16 + crow + r;
                float z = acc[mt][n2][r] + sDist[row] * wl + bb;
                sX[row][col] = f2bf(silu_f(z));
            }
        }
    }
    __syncthreads();   // B3

    // ----- msg layer 2 : sX @ W2 + b2 = messages -> sY (K=128) -----
#pragma unroll
    for (int mt = 0; mt < 4; ++mt) {
        acc[mt][0] = (f32x4){0.f, 0.f, 0.f, 0.f};
        acc[mt][1] = (f32x4){0.f, 0.f, 0.f, 0.f};
    }
#pragma unroll
    for (int kt = 0; kt < 4; ++kt) {
        const int kk = kt * 32 + kq;
        bf16x8 bw0 = *(const bf16x8*)(fW2 + (size_t)(((kt * 8 + nt0) * 64 + lane) * 8));
        bf16x8 bw1 = *(const bf16x8*)(fW2 + (size_t)(((kt * 8 + nt0 + 1) * 64 + lane) * 8));
#pragma unroll
        for (int mt = 0; mt < 4; ++mt) {
            bf16x8 a = *(const bf16x8*)(&sX[0][0] + (mt * 16 + mrow) * 136 + kk);
            acc[mt][0] = MFMA(a, bw0, acc[mt][0]);
            acc[mt][1] = MFMA(a, bw1, acc[mt][1]);
        }
    }
    // messages -> sY (h_dst dead since B2)
#pragma unroll
    for (int mt = 0; mt < 4; ++mt) {
#pragma unroll
        for (int n2 = 0; n2 < 2; ++n2) {
            const int col = (nt0 + n2) * 16 + ccol;
            const float bb = bf2f(bias2[col]);
#pragma unroll
            for (int r = 0; r < 4; ++r) {
                const int row = mt * 16 + crow + r;
                sY[row][col] = f2bf(acc[mt][n2][r] + bb);
            }
        }
    }
    __syncthreads();   // B4: messages visible; all L2 reads of sX done

    // ----- pos layer 1 : silu(messages @ P1 + bp1) -> sX (K=128) -----
#pragma unroll
    for (int mt = 0; mt < 4; ++mt) {
        acc[mt][0] = (f32x4){0.f, 0.f, 0.f, 0.f};
        acc[mt][1] = (f32x4){0.f, 0.f, 0.f, 0.f};
    }
#pragma unroll
    for (int kt = 0; kt < 4; ++kt) {
        const int kk = kt * 32 + kq;
        bf16x8 bw0 = *(const bf16x8*)(fP1 + (size_t)(((kt * 8 + nt0) * 64 + lane) * 8));
        bf16x8 bw1 = *(const bf16x8*)(fP1 + (size_t)(((kt * 8 + nt0 + 1) * 64 + lane) * 8));
#pragma unroll
        for (int mt = 0; mt < 4; ++mt) {
            bf16x8 a = *(const bf16x8*)(&sY[0][0] + (mt * 16 + mrow) * 136 + kk);
            acc[mt][0] = MFMA(a, bw0, acc[mt][0]);
            acc[mt][1] = MFMA(a, bw1, acc[mt][1]);
        }
    }

    // scatter messages from sY via packed bf16x2 atomics:
    // thread owns one row x one 32-col (64B-line) chunk -> 16 pk atomics
    {
        const int r = tid >> 2;
        const int c0 = (tid & 3) * 32;
        const size_t base = ((size_t)sBat[r] * NN + sDst[r]) * HH + c0;
        const unsigned int* src = (const unsigned int*)&sY[r][c0];
#pragma unroll
        for (int i = 0; i < 16; ++i) pk_add(agg + base + 2 * i, src[i]);
    }

    // pos1 epilogue -> sX (all L2 reads of sX done at B4)
#pragma unroll
    for (int mt = 0; mt < 4; ++mt) {
#pragma unroll
        for (int n2 = 0; n2 < 2; ++n2) {
            const int col = (nt0 + n2) * 16 + ccol;
            const float bb = bf2f(biasp1[col]);
#pragma unroll
            for (int r = 0; r < 4; ++r) {
                const int row = mt * 16 + crow + r;
                sX[row][col] = f2bf(silu_f(acc[mt][n2][r] + bb));
            }
        }
    }
    __syncthreads();   // B5

    // ----- pos layer 2 : tanh(hidden @ p2 + bp2) ; scatter wgt*rel_pos -----
    {
        const int r = tid >> 2, q = tid & 3;
        const u16* trow = &sX[r][q * 32];
        const u16* wrow = wp2 + q * 32;
        float p = 0.f;
#pragma unroll
        for (int k = 0; k < 32; ++k) p += bf2f(trow[k]) * bf2f(wrow[k]);
        p += __shfl_xor(p, 1);
        p += __shfl_xor(p, 2);
        if (q == 0) {
            float wgt = tanhf(p + bf2f(biasp2[0]));
            const size_t pb = ((size_t)sBat[r] * NN + sDst[r]) * 3;
            unsafeAtomicAdd(&pos_acc[pb + 0], wgt * sRel[r][0]);
            unsafeAtomicAdd(&pos_acc[pb + 1], wgt * sRel[r][1]);
            unsafeAtomicAdd(&pos_acc[pb + 2], wgt * sRel[r][2]);
        }
    }
}

__global__ __launch_bounds__(256) void update_kernel(
    const u16* __restrict__ feat, const void* __restrict__ rawfeat,
    const u16* __restrict__ dgu, const u16* __restrict__ dgd,
    const u16* __restrict__ aggu, const u16* __restrict__ aggd,
    const u16* __restrict__ fU1, const u16* __restrict__ bu1,
    const u16* __restrict__ fU2, const u16* __restrict__ bu2,
    void* __restrict__ outp, const int* __restrict__ flag)
{
    const int tid = threadIdx.x;
    const int lane = tid & 63;
    const int wv = tid >> 6;
    const int row0 = blockIdx.x * 64;   // node-instance rows
    const int isf = *flag;

    __shared__ u16 sA[64][136];   // features (bf16)
    __shared__ u16 sB[64][136];   // msg_acc (bf16)
    __shared__ u16 sY[64][136];   // hidden

    {
        const uint4* src = (const uint4*)(feat + (size_t)row0 * HH);
        for (int i = tid; i < 1024; i += 256) {
            int r = i >> 4, c = i & 15;
            *(uint4*)&sA[r][c * 8] = src[i];
        }
        const uint4* au = (const uint4*)(aggu) + (size_t)row0 * 16;  // 16 uint4 / row
        const uint4* ad = (const uint4*)(aggd) + (size_t)row0 * 16;
        for (int i = tid; i < 1024; i += 256) {
            int r = i >> 4;
            int inst = row0 + r;
            int n = (inst >= NN) ? inst - NN : inst;
            float iu = 1.f / fmaxf(bf2f(dgu[n]), 1.f);
            float id = 1.f / fmaxf(bf2f(dgd[n]), 1.f);
            uint4 u4 = au[i], d4 = ad[i];
            const u16* up = (const u16*)&u4;
            const u16* dp = (const u16*)&d4;
            int c = (i & 15) * 8;
#pragma unroll
            for (int j = 0; j < 8; ++j)
                sB[r][c + j] = f2bf(bf2f(up[j]) * iu + bf2f(dp[j]) * id);
        }
    }
    __syncthreads();

    const int nt0 = wv * 2;
    const int mrow = lane & 15;
    const int kq = (lane >> 4) * 8;
    const int crow = (lane >> 4) * 4;
    const int ccol = lane & 15;

    f32x4 acc[4][2];
#pragma unroll
    for (int mt = 0; mt < 4; ++mt) {
        acc[mt][0] = (f32x4){0.f, 0.f, 0.f, 0.f};
        acc[mt][1] = (f32x4){0.f, 0.f, 0.f, 0.f};
    }
    // layer 1: [features | msg_acc] @ w_upd1 (K=256), silu
#pragma unroll
    for (int kt = 0; kt < 8; ++kt) {
        const u16* Xb = (kt < 4) ? &sA[0][0] : &sB[0][0];
        const int kk = (kt & 3) * 32 + kq;
        bf16x8 bw0 = *(const bf16x8*)(fU1 + (size_t)(((kt * 8 + nt0) * 64 + lane) * 8));
        bf16x8 bw1 = *(const bf16x8*)(fU1 + (size_t)(((kt * 8 + nt0 + 1) * 64 + lane) * 8));
#pragma unroll
        for (int mt = 0; mt < 4; ++mt) {
            bf16x8 a = *(const bf16x8*)(Xb + (mt * 16 + mrow) * 136 + kk);
            acc[mt][0] = MFMA(a, bw0, acc[mt][0]);
            acc[mt][1] = MFMA(a, bw1, acc[mt][1]);
        }
    }
#pragma unroll
    for (int mt = 0; mt < 4; ++mt) {
#pragma unroll
        for (int n2 = 0; n2 < 2; ++n2) {
            const int col = (nt0 + n2) * 16 + ccol;
            const float bb = bf2f(bu1[col]);
#pragma unroll
            for (int r = 0; r < 4; ++r) {
                const int row = mt * 16 + crow + r;
                sY[row][col] = f2bf(silu_f(acc[mt][n2][r] + bb));
            }
        }
    }
    __syncthreads();

    // layer 2 + residual -> out
#pragma unroll
    for (int mt = 0; mt < 4; ++mt) {
        acc[mt][0] = (f32x4){0.f, 0.f, 0.f, 0.f};
        acc[mt][1] = (f32x4){0.f, 0.f, 0.f, 0.f};
    }
#pragma unroll
    for (int kt = 0; kt < 4; ++kt) {
        const int kk = kt * 32 + kq;
        bf16x8 bw0 = *(const bf16x8*)(fU2 + (size_t)(((kt * 8 + nt0) * 64 + lane) * 8));
        bf16x8 bw1 = *(const bf16x8*)(fU2 + (size_t)(((kt * 8 + nt0 + 1) * 64 + lane) * 8));
#pragma unroll
        for (int mt = 0; mt < 4; ++mt) {
            bf16x8 a = *(const bf16x8*)(&sY[0][0] + (mt * 16 + mrow) * 136 + kk);
            acc[mt][0] = MFMA(a, bw0, acc[mt][0]);
            acc[mt][1] = MFMA(a, bw1, acc[mt][1]);
        }
    }
#pragma unroll
    for (int mt = 0; mt < 4; ++mt) {
#pragma unroll
        for (int n2 = 0; n2 < 2; ++n2) {
            const int col = (nt0 + n2) * 16 + ccol;
            const float bb = bf2f(bu2[col]);
#pragma unroll
            for (int r = 0; r < 4; ++r) {
                const int row = mt * 16 + crow + r;
                const size_t idx = (size_t)(row0 + row) * HH + col;
                if (isf) {
                    float base = ((const float*)rawfeat)[idx];
                    ((float*)outp)[idx] = acc[mt][n2][r] + bb + base;
                } else {
                    float base = bf2f(sA[row][col]);
                    ((u16*)outp)[idx] = f2bf(acc[mt][n2][r] + bb + base);
                }
            }
        }
    }
}

__global__ void pos_out_kernel(const void* __restrict__ rawpos, const u16* __restrict__ cpos,
                               const float* __restrict__ pacc, void* __restrict__ outp,
                               const int* __restrict__ flag)
{
    int i = blockIdx.x * 256 + threadIdx.x;
    if (i >= BB * NN * 3) return;
    if (*flag) {
        float base = ((const float*)rawpos)[i];
        ((float*)outp)[5120000 + i] = base + 0.5f * pacc[i];
    } else {
        float base = bf2f(cpos[i]);
        ((u16*)outp)[5120000 + i] = f2bf(base + 0.5f * pacc[i]);
    }
}

extern "C" void kernel_launch(void* const* d_in, const int* in_sizes, int n_in,
                              void* d_out, int out_size, void* d_ws, size_t ws_size,
                              hipStream_t stream)
{
    // workspace layout (bytes):
    //   [0, 10,240,000)            agg_up  (bf16, memset 0)
    //   [10,240,000, 20,480,000)   agg_dn  (bf16, memset 0)
    //   [20,480,000, 20,960,000)   pos_acc (f32,  memset 0)
    //   [20,960,000, 21,320,448)   weight fragments (180,224 u16)
    //   [21,320,448, 32,244,000)   canonical bf16 inputs (5,461,776 u16)
    //   [32,244,000, +4)           dtype flag
    u16*   agg_up  = (u16*)d_ws;
    u16*   agg_dn  = (u16*)((char*)d_ws + 10240000);
    float* pos_acc = (float*)((char*)d_ws + 20480000);
    const size_t ZERO_BYTES = 20960000;
    u16* fbase = (u16*)((char*)d_ws + 20960000);
    u16* canon = (u16*)((char*)d_ws + 21320448);
    int* flag  = (int*)((char*)d_ws + 32244000);
    if (ws_size < 32244008ULL) return;

    u16* f_m1u = fbase;              // 32768 (K=256)
    u16* f_m2u = fbase + 32768;      // 16384 (K=128)
    u16* f_p1u = fbase + 49152;      // 16384
    u16* f_m1d = fbase + 65536;      // 32768
    u16* f_m2d = fbase + 98304;      // 16384
    u16* f_p1d = fbase + 114688;     // 16384
    u16* f_u1  = fbase + 131072;     // 32768
    u16* f_u2  = fbase + 163840;     // 16384

    // canonical tensor pointers
    u16* cfeat = canon;
    u16* cpos  = canon + 5120000;
    u16* cdgu  = canon + 5240000;
    u16* cdgd  = canon + 5260000;
    u16* cm1u  = canon + 5280000;
    u16* cbm1u = canon + 5312896;
    u16* cm2u  = canon + 5313024;
    u16* cbm2u = canon + 5329408;
    u16* cp1u  = canon + 5329536;
    u16* cbp1u = canon + 5345920;
    u16* cp2u  = canon + 5346048;
    u16* cbp2u = canon + 5346176;
    u16* cm1d  = canon + 5346184;
    u16* cbm1d = canon + 5379080;
    u16* cm2d  = canon + 5379208;
    u16* cbm2d = canon + 5395592;
    u16* cp1d  = canon + 5395720;
    u16* cbp1d = canon + 5412104;
    u16* cp2d  = canon + 5412232;
    u16* cbp2d = canon + 5412360;
    u16* cu1   = canon + 5412368;
    u16* cbu1  = canon + 5445136;
    u16* cu2   = canon + 5445264;
    u16* cbu2  = canon + 5461648;

    hipMemsetAsync(d_ws, 0, ZERO_BYTES, stream);

    detect_kernel<<<1, 256, 0, stream>>>((const u16*)d_in[0], flag);

    P24 ptrs;
    ptrs.p[0] = d_in[0];  ptrs.p[1] = d_in[1];  ptrs.p[2] = d_in[4];  ptrs.p[3] = d_in[5];
    ptrs.p[4] = d_in[6];  ptrs.p[5] = d_in[7];  ptrs.p[6] = d_in[8];  ptrs.p[7] = d_in[9];
    ptrs.p[8] = d_in[10]; ptrs.p[9] = d_in[11]; ptrs.p[10] = d_in[12]; ptrs.p[11] = d_in[13];
    ptrs.p[12] = d_in[14]; ptrs.p[13] = d_in[15]; ptrs.p[14] = d_in[16]; ptrs.p[15] = d_in[17];
    ptrs.p[16] = d_in[18]; ptrs.p[17] = d_in[19]; ptrs.p[18] = d_in[20]; ptrs.p[19] = d_in[21];
    ptrs.p[20] = d_in[22]; ptrs.p[21] = d_in[23]; ptrs.p[22] = d_in[24]; ptrs.p[23] = d_in[25];
    canon_kernel<<<(CTOT + 255) / 256, 256, 0, stream>>>(ptrs, flag, canon);

    make_frag<<<128, 256, 0, stream>>>(cm1u, f_m1u);
    make_frag<<<64,  256, 0, stream>>>(cm2u, f_m2u);
    make_frag<<<64,  256, 0, stream>>>(cp1u, f_p1u);
    make_frag<<<128, 256, 0, stream>>>(cm1d, f_m1d);
    make_frag<<<64,  256, 0, stream>>>(cm2d, f_m2d);
    make_frag<<<64,  256, 0, stream>>>(cp1d, f_p1d);
    make_frag<<<128, 256, 0, stream>>>(cu1,  f_u1);
    make_frag<<<64,  256, 0, stream>>>(cu2,  f_u2);

    const int* ei_up = (const int*)d_in[2];
    const int* ei_dn = (const int*)d_in[3];

    edge_kernel<<<6250, 256, 0, stream>>>(
        cfeat, cpos, ei_up,
        f_m1u, cm1u + 256 * 128, cbm1u,
        f_m2u, cbm2u,
        f_p1u, cbp1u, cp2u, cbp2u,
        agg_up, pos_acc);
    edge_kernel<<<6250, 256, 0, stream>>>(
        cfeat, cpos, ei_dn,
        f_m1d, cm1d + 256 * 128, cbm1d,
        f_m2d, cbm2d,
        f_p1d, cbp1d, cp2d, cbp2d,
        agg_dn, pos_acc);

    update_kernel<<<625, 256, 0, stream>>>(
        cfeat, d_in[0], cdgu, cdgd, agg_up, agg_dn,
        f_u1, cbu1, f_u2, cbu2, d_out, flag);

    pos_out_kernel<<<469, 256, 0, stream>>>(d_in[1], cpos, pos_acc, d_out, flag);
}

// Round 4
// 614.584 us; speedup vs baseline: 5.2072x; 5.2072x over previous
//
#include <hip/hip_runtime.h>

#define BB 2
#define NN 20000
#define HH 128
#define EE 200000
#define EBLK 3125   // EE / 64

typedef unsigned short u16;
typedef __attribute__((ext_vector_type(4))) float f32x4;
typedef __bf16 bf16x8 __attribute__((ext_vector_type(8)));

#define MFMA(a, b, c) __builtin_amdgcn_mfma_f32_16x16x32_bf16((a), (b), (c), 0, 0, 0)

__device__ __forceinline__ float bf2f(u16 u) {
    union { unsigned int i; float f; } v; v.i = ((unsigned int)u) << 16; return v.f;
}
__device__ __forceinline__ u16 f2bf(float f) {
    union { float f; unsigned int i; } v; v.f = f;
    unsigned int r = (v.i + 0x7FFFu + ((v.i >> 16) & 1u)) >> 16;
    return (u16)r;
}
__device__ __forceinline__ float silu_f(float z) { return z / (1.f + __expf(-z)); }

// ---------------- dtype detection ----------------
__global__ void detect_kernel(const u16* __restrict__ f, int* __restrict__ flag) {
    int tid = threadIdx.x;
    u16 v = f[tid * 2];
    int e = (v >> 7) & 0xFF;
    int ok = (e >= 101 && e <= 143) ? 1 : 0;
    __shared__ int cnt;
    if (tid == 0) cnt = 0;
    __syncthreads();
    atomicAdd(&cnt, ok);
    __syncthreads();
    if (tid == 0) *flag = (cnt < 200) ? 1 : 0;   // 1 => inputs are float32
}

// ---------------- canonicalize all float inputs to bf16 in ws ----------------
#define CTOT 5461776
struct P24 { const void* p[24]; };

__global__ __launch_bounds__(256) void canon_kernel(P24 ptrs, const int* __restrict__ flag,
                                                    u16* __restrict__ canon) {
    static const int off[25] = {
        0, 5120000, 5240000, 5260000, 5280000, 5312896, 5313024, 5329408,
        5329536, 5345920, 5346048, 5346176, 5346184, 5379080, 5379208, 5395592,
        5395720, 5412104, 5412232, 5412360, 5412368, 5445136, 5445264, 5461648,
        5461776 };
    static const int rsz[24] = {
        5120000, 120000, 20000, 20000,
        32896, 128, 16384, 128, 16384, 128, 128, 1,
        32896, 128, 16384, 128, 16384, 128, 128, 1,
        32768, 128, 16384, 128 };
    int i = blockIdx.x * 256 + threadIdx.x;
    if (i >= CTOT) return;
    int t = 0;
#pragma unroll 1
    while (i >= off[t + 1]) ++t;
    int j = i - off[t];
    u16 v;
    if (j >= rsz[t]) v = 0;
    else if (*flag) v = f2bf(((const float*)ptrs.p[t])[j]);
    else v = ((const u16*)ptrs.p[t])[j];
    canon[i] = v;
}

// ---------------- weight fragment permutation ----------------
__global__ void make_frag(const u16* __restrict__ W, u16* __restrict__ F) {
    int tid = blockIdx.x * 256 + threadIdx.x;
    int j = tid & 7, lane = (tid >> 3) & 63, nt = (tid >> 9) & 7, kt = tid >> 12;
    int k = kt * 32 + ((lane >> 4) * 8) + j;
    int n = nt * 16 + (lane & 15);
    F[tid] = W[k * 128 + n];
}

// ---------------- CSR build: count -> scan -> cursor scatter ----------------
__global__ void count_kernel(const int* __restrict__ eidx, int* __restrict__ cnt) {
    int e = blockIdx.x * 256 + threadIdx.x;
    if (e < EE) atomicAdd(&cnt[eidx[EE + e]], 1);
}

__global__ __launch_bounds__(1024) void scan_kernel(const int* __restrict__ cnt,
                                                    int* __restrict__ cur) {
    __shared__ int buf[1024];
    __shared__ int carry;
    if (threadIdx.x == 0) carry = 0;
    __syncthreads();
    for (int base = 0; base < NN; base += 1024) {
        int i = base + threadIdx.x;
        int v = (i < NN) ? cnt[i] : 0;
        buf[threadIdx.x] = v;
        __syncthreads();
        for (int s = 1; s < 1024; s <<= 1) {
            int t = (threadIdx.x >= s) ? buf[threadIdx.x - s] : 0;
            __syncthreads();
            buf[threadIdx.x] += t;
            __syncthreads();
        }
        int inc = buf[threadIdx.x];
        if (i < NN) cur[i] = carry + inc - v;   // exclusive prefix
        __syncthreads();
        if (threadIdx.x == 1023) carry += inc;
        __syncthreads();
    }
}

__global__ void scatter_kernel(const int* __restrict__ eidx, int* __restrict__ cur,
                               int* __restrict__ es) {
    int e = blockIdx.x * 256 + threadIdx.x;
    if (e < EE) {
        int p = atomicAdd(&cur[eidx[EE + e]], 1);
        es[p] = e;
    }
}

// ---------------- edge kernel: dst-sorted slots, segment-reduced atomics ----
__global__ __launch_bounds__(256, 4) void edge_kernel(
    const u16* __restrict__ feat, const u16* __restrict__ posit,
    const int* __restrict__ eidx, const int* __restrict__ es,
    const u16* __restrict__ deg,
    const u16* __restrict__ fW1, const u16* __restrict__ w1last, const u16* __restrict__ bias1,
    const u16* __restrict__ fW2, const u16* __restrict__ bias2,
    const u16* __restrict__ fP1, const u16* __restrict__ biasp1,
    const u16* __restrict__ wp2, const u16* __restrict__ biasp2,
    float* __restrict__ msg_acc, float* __restrict__ pos_acc)
{
    const int tid = threadIdx.x;
    const int lane = tid & 63;
    const int wv = tid >> 6;
    const int bb = blockIdx.x / EBLK;                 // batch
    const int s0 = (blockIdx.x - bb * EBLK) * 64;     // slot base

    __shared__ u16 sX[64][136];   // h_src -> msg-hidden -> pos-hidden
    __shared__ u16 sY[64][136];   // h_dst -> messages
    __shared__ float sRel[64][3];
    __shared__ float sDist[64];
    __shared__ float sInv[64];
    __shared__ int sSrc[64], sDst[64];

    if (tid < 64) {
        int e = es[s0 + tid];
        int s = eidx[e];
        int d = eidx[EE + e];
        sSrc[tid] = s; sDst[tid] = d;
        sInv[tid] = 1.f / fmaxf(bf2f(deg[d]), 1.f);
        const u16* ps = posit + ((size_t)bb * NN + s) * 3;
        const u16* pd = posit + ((size_t)bb * NN + d) * 3;
        float dx = bf2f(ps[0]) - bf2f(pd[0]);
        float dy = bf2f(ps[1]) - bf2f(pd[1]);
        float dz = bf2f(ps[2]) - bf2f(pd[2]);
        sRel[tid][0] = dx; sRel[tid][1] = dy; sRel[tid][2] = dz;
        sDist[tid] = sqrtf(dx * dx + dy * dy + dz * dz);
    }
    __syncthreads();   // B0

    // gather h_src -> sX, h_dst -> sY (dst rows repeat -> L1 hits)
    {
        const int r = tid >> 2, part = tid & 3;
        const uint4* fs = (const uint4*)(feat + ((size_t)bb * NN + sSrc[r]) * HH);
        const uint4* fd = (const uint4*)(feat + ((size_t)bb * NN + sDst[r]) * HH);
        uint4* as = (uint4*)&sX[r][part * 32];
        uint4* ad = (uint4*)&sY[r][part * 32];
#pragma unroll
        for (int i = 0; i < 4; ++i) { as[i] = fs[part * 4 + i]; ad[i] = fd[part * 4 + i]; }
    }
    __syncthreads();   // B1

    const int nt0 = wv * 2;
    const int mrow = lane & 15;
    const int kq = (lane >> 4) * 8;
    const int crow = (lane >> 4) * 4;
    const int ccol = lane & 15;

    f32x4 acc[4][2];
#pragma unroll
    for (int mt = 0; mt < 4; ++mt) {
        acc[mt][0] = (f32x4){0.f, 0.f, 0.f, 0.f};
        acc[mt][1] = (f32x4){0.f, 0.f, 0.f, 0.f};
    }

    // ----- msg layer 1 : [h_src | h_dst] @ W1[0:256]  (K=256) -----
#pragma unroll
    for (int kt = 0; kt < 8; ++kt) {
        const u16* Xb = (kt < 4) ? &sX[0][0] : &sY[0][0];
        const int kk = (kt & 3) * 32 + kq;
        bf16x8 bw0 = *(const bf16x8*)(fW1 + (size_t)(((kt * 8 + nt0) * 64 + lane) * 8));
        bf16x8 bw1 = *(const bf16x8*)(fW1 + (size_t)(((kt * 8 + nt0 + 1) * 64 + lane) * 8));
#pragma unroll
        for (int mt = 0; mt < 4; ++mt) {
            bf16x8 a = *(const bf16x8*)(Xb + (mt * 16 + mrow) * 136 + kk);
            acc[mt][0] = MFMA(a, bw0, acc[mt][0]);
            acc[mt][1] = MFMA(a, bw1, acc[mt][1]);
        }
    }
    __syncthreads();   // B2: all L1 reads of sX/sY done

    // epilogue: + dist*W1[256] + b1, silu -> sX
#pragma unroll
    for (int mt = 0; mt < 4; ++mt) {
#pragma unroll
        for (int n2 = 0; n2 < 2; ++n2) {
            const int col = (nt0 + n2) * 16 + ccol;
            const float wl = bf2f(w1last[col]);
            const float bb2 = bf2f(bias1[col]);
#pragma unroll
            for (int r = 0; r < 4; ++r) {
                const int row = mt * 16 + crow + r;
                float z = acc[mt][n2][r] + sDist[row] * wl + bb2;
                sX[row][col] = f2bf(silu_f(z));
            }
        }
    }
    __syncthreads();   // B3

    // ----- msg layer 2 : sX @ W2 + b2 = messages -> sY (K=128) -----
#pragma unroll
    for (int mt = 0; mt < 4; ++mt) {
        acc[mt][0] = (f32x4){0.f, 0.f, 0.f, 0.f};
        acc[mt][1] = (f32x4){0.f, 0.f, 0.f, 0.f};
    }
#pragma unroll
    for (int kt = 0; kt < 4; ++kt) {
        const int kk = kt * 32 + kq;
        bf16x8 bw0 = *(const bf16x8*)(fW2 + (size_t)(((kt * 8 + nt0) * 64 + lane) * 8));
        bf16x8 bw1 = *(const bf16x8*)(fW2 + (size_t)(((kt * 8 + nt0 + 1) * 64 + lane) * 8));
#pragma unroll
        for (int mt = 0; mt < 4; ++mt) {
            bf16x8 a = *(const bf16x8*)(&sX[0][0] + (mt * 16 + mrow) * 136 + kk);
            acc[mt][0] = MFMA(a, bw0, acc[mt][0]);
            acc[mt][1] = MFMA(a, bw1, acc[mt][1]);
        }
    }
#pragma unroll
    for (int mt = 0; mt < 4; ++mt) {
#pragma unroll
        for (int n2 = 0; n2 < 2; ++n2) {
            const int col = (nt0 + n2) * 16 + ccol;
            const float bb2 = bf2f(bias2[col]);
#pragma unroll
            for (int r = 0; r < 4; ++r) {
                const int row = mt * 16 + crow + r;
                sY[row][col] = f2bf(acc[mt][n2][r] + bb2);
            }
        }
    }
    __syncthreads();   // B4: messages visible; all L2 reads of sX done

    // ----- pos layer 1 : silu(messages @ P1 + bp1) -> sX (K=128) -----
#pragma unroll
    for (int mt = 0; mt < 4; ++mt) {
        acc[mt][0] = (f32x4){0.f, 0.f, 0.f, 0.f};
        acc[mt][1] = (f32x4){0.f, 0.f, 0.f, 0.f};
    }
#pragma unroll
    for (int kt = 0; kt < 4; ++kt) {
        const int kk = kt * 32 + kq;
        bf16x8 bw0 = *(const bf16x8*)(fP1 + (size_t)(((kt * 8 + nt0) * 64 + lane) * 8));
        bf16x8 bw1 = *(const bf16x8*)(fP1 + (size_t)(((kt * 8 + nt0 + 1) * 64 + lane) * 8));
#pragma unroll
        for (int mt = 0; mt < 4; ++mt) {
            bf16x8 a = *(const bf16x8*)(&sY[0][0] + (mt * 16 + mrow) * 136 + kk);
            acc[mt][0] = MFMA(a, bw0, acc[mt][0]);
            acc[mt][1] = MFMA(a, bw1, acc[mt][1]);
        }
    }

    // segment-reduced scatter of messages (rows sorted by dst):
    // 2 threads per column (rows 0-31 / 32-63); flush one f32 atomic per
    // (dst-segment x column), pre-scaled by 1/clip(deg) so both
    // neighborhoods share one msg_acc buffer.
    {
        const int col = tid & 127;
        const int r0 = (tid >> 7) * 32;
        float accv = 0.f;
        int dprev = sDst[r0];
        float invprev = sInv[r0];
#pragma unroll 1
        for (int r = r0; r < r0 + 32; ++r) {
            int dcur = sDst[r];
            if (dcur != dprev) {
                unsafeAtomicAdd(&msg_acc[((size_t)bb * NN + dprev) * HH + col], accv * invprev);
                accv = 0.f; dprev = dcur; invprev = sInv[r];
            }
            accv += bf2f(sY[r][col]);
        }
        unsafeAtomicAdd(&msg_acc[((size_t)bb * NN + dprev) * HH + col], accv * invprev);
    }

    // pos1 epilogue -> sX
#pragma unroll
    for (int mt = 0; mt < 4; ++mt) {
#pragma unroll
        for (int n2 = 0; n2 < 2; ++n2) {
            const int col = (nt0 + n2) * 16 + ccol;
            const float bb2 = bf2f(biasp1[col]);
#pragma unroll
            for (int r = 0; r < 4; ++r) {
                const int row = mt * 16 + crow + r;
                sX[row][col] = f2bf(silu_f(acc[mt][n2][r] + bb2));
            }
        }
    }
    __syncthreads();   // B5

    // ----- pos layer 2 : tanh(hidden @ p2 + bp2) ; scatter wgt*rel_pos -----
    {
        const int r = tid >> 2, q = tid & 3;
        const u16* trow = &sX[r][q * 32];
        const u16* wrow = wp2 + q * 32;
        float p = 0.f;
#pragma unroll
        for (int k = 0; k < 32; ++k) p += bf2f(trow[k]) * bf2f(wrow[k]);
        p += __shfl_xor(p, 1);
        p += __shfl_xor(p, 2);
        if (q == 0) {
            float wgt = tanhf(p + bf2f(biasp2[0]));
            const size_t pb = ((size_t)bb * NN + sDst[r]) * 3;
            unsafeAtomicAdd(&pos_acc[pb + 0], wgt * sRel[r][0]);
            unsafeAtomicAdd(&pos_acc[pb + 1], wgt * sRel[r][1]);
            unsafeAtomicAdd(&pos_acc[pb + 2], wgt * sRel[r][2]);
        }
    }
}

__global__ __launch_bounds__(256) void update_kernel(
    const u16* __restrict__ feat, const void* __restrict__ rawfeat,
    const float* __restrict__ magg,
    const u16* __restrict__ fU1, const u16* __restrict__ bu1,
    const u16* __restrict__ fU2, const u16* __restrict__ bu2,
    void* __restrict__ outp, const int* __restrict__ flag)
{
    const int tid = threadIdx.x;
    const int lane = tid & 63;
    const int wv = tid >> 6;
    const int row0 = blockIdx.x * 64;   // node-instance rows
    const int isf = *flag;

    __shared__ u16 sA[64][136];   // features (bf16)
    __shared__ u16 sB[64][136];   // msg_acc (bf16)
    __shared__ u16 sY[64][136];   // hidden

    {
        const uint4* src = (const uint4*)(feat + (size_t)row0 * HH);
        for (int i = tid; i < 1024; i += 256) {
            int r = i >> 4, c = i & 15;
            *(uint4*)&sA[r][c * 8] = src[i];
        }
        const float4* am = (const float4*)(magg) + (size_t)row0 * 32;
        for (int i = tid; i < 2048; i += 256) {
            int r = i >> 5;
            float4 v = am[i];
            int c = (i & 31) * 4;
            sB[r][c + 0] = f2bf(v.x);
            sB[r][c + 1] = f2bf(v.y);
            sB[r][c + 2] = f2bf(v.z);
            sB[r][c + 3] = f2bf(v.w);
        }
    }
    __syncthreads();

    const int nt0 = wv * 2;
    const int mrow = lane & 15;
    const int kq = (lane >> 4) * 8;
    const int crow = (lane >> 4) * 4;
    const int ccol = lane & 15;

    f32x4 acc[4][2];
#pragma unroll
    for (int mt = 0; mt < 4; ++mt) {
        acc[mt][0] = (f32x4){0.f, 0.f, 0.f, 0.f};
        acc[mt][1] = (f32x4){0.f, 0.f, 0.f, 0.f};
    }
    // layer 1: [features | msg_acc] @ w_upd1 (K=256), silu
#pragma unroll
    for (int kt = 0; kt < 8; ++kt) {
        const u16* Xb = (kt < 4) ? &sA[0][0] : &sB[0][0];
        const int kk = (kt & 3) * 32 + kq;
        bf16x8 bw0 = *(const bf16x8*)(fU1 + (size_t)(((kt * 8 + nt0) * 64 + lane) * 8));
        bf16x8 bw1 = *(const bf16x8*)(fU1 + (size_t)(((kt * 8 + nt0 + 1) * 64 + lane) * 8));
#pragma unroll
        for (int mt = 0; mt < 4; ++mt) {
            bf16x8 a = *(const bf16x8*)(Xb + (mt * 16 + mrow) * 136 + kk);
            acc[mt][0] = MFMA(a, bw0, acc[mt][0]);
            acc[mt][1] = MFMA(a, bw1, acc[mt][1]);
        }
    }
#pragma unroll
    for (int mt = 0; mt < 4; ++mt) {
#pragma unroll
        for (int n2 = 0; n2 < 2; ++n2) {
            const int col = (nt0 + n2) * 16 + ccol;
            const float bb = bf2f(bu1[col]);
#pragma unroll
            for (int r = 0; r < 4; ++r) {
                const int row = mt * 16 + crow + r;
                sY[row][col] = f2bf(silu_f(acc[mt][n2][r] + bb));
            }
        }
    }
    __syncthreads();

    // layer 2 + residual -> out
#pragma unroll
    for (int mt = 0; mt < 4; ++mt) {
        acc[mt][0] = (f32x4){0.f, 0.f, 0.f, 0.f};
        acc[mt][1] = (f32x4){0.f, 0.f, 0.f, 0.f};
    }
#pragma unroll
    for (int kt = 0; kt < 4; ++kt) {
        const int kk = kt * 32 + kq;
        bf16x8 bw0 = *(const bf16x8*)(fU2 + (size_t)(((kt * 8 + nt0) * 64 + lane) * 8));
        bf16x8 bw1 = *(const bf16x8*)(fU2 + (size_t)(((kt * 8 + nt0 + 1) * 64 + lane) * 8));
#pragma unroll
        for (int mt = 0; mt < 4; ++mt) {
            bf16x8 a = *(const bf16x8*)(&sY[0][0] + (mt * 16 + mrow) * 136 + kk);
            acc[mt][0] = MFMA(a, bw0, acc[mt][0]);
            acc[mt][1] = MFMA(a, bw1, acc[mt][1]);
        }
    }
#pragma unroll
    for (int mt = 0; mt < 4; ++mt) {
#pragma unroll
        for (int n2 = 0; n2 < 2; ++n2) {
            const int col = (nt0 + n2) * 16 + ccol;
            const float bb = bf2f(bu2[col]);
#pragma unroll
            for (int r = 0; r < 4; ++r) {
                const int row = mt * 16 + crow + r;
                const size_t idx = (size_t)(row0 + row) * HH + col;
                if (isf) {
                    float base = ((const float*)rawfeat)[idx];
                    ((float*)outp)[idx] = acc[mt][n2][r] + bb + base;
                } else {
                    float base = bf2f(sA[row][col]);
                    ((u16*)outp)[idx] = f2bf(acc[mt][n2][r] + bb + base);
                }
            }
        }
    }
}

__global__ void pos_out_kernel(const void* __restrict__ rawpos, const u16* __restrict__ cpos,
                               const float* __restrict__ pacc, void* __restrict__ outp,
                               const int* __restrict__ flag)
{
    int i = blockIdx.x * 256 + threadIdx.x;
    if (i >= BB * NN * 3) return;
    if (*flag) {
        float base = ((const float*)rawpos)[i];
        ((float*)outp)[5120000 + i] = base + 0.5f * pacc[i];
    } else {
        float base = bf2f(cpos[i]);
        ((u16*)outp)[5120000 + i] = f2bf(base + 0.5f * pacc[i]);
    }
}

extern "C" void kernel_launch(void* const* d_in, const int* in_sizes, int n_in,
                              void* d_out, int out_size, void* d_ws, size_t ws_size,
                              hipStream_t stream)
{
    // workspace layout (bytes):
    //   [0,          20,480,000)  msg_acc f32 (memset 0)
    //   [20,480,000, 20,960,000)  pos_acc f32 (memset 0)
    //   [20,960,000, 21,040,000)  cnt_up  (memset 0)
    //   [21,040,000, 21,120,000)  cnt_dn  (memset 0)
    //   [21,120,000, 21,200,000)  cur_up
    //   [21,200,000, 21,280,000)  cur_dn
    //   [21,280,000, 22,080,000)  es_up (sorted edge ids)
    //   [22,080,000, 22,880,000)  es_dn
    //   [22,880,000, 23,240,448)  weight fragments (180,224 u16)
    //   [23,240,448, 34,164,000)  canonical bf16 inputs (5,461,776 u16)
    //   [34,164,000, +4)          dtype flag
    float* msg_acc = (float*)d_ws;
    float* pos_acc = (float*)((char*)d_ws + 20480000);
    int*   cnt_up  = (int*)((char*)d_ws + 20960000);
    int*   cnt_dn  = (int*)((char*)d_ws + 21040000);
    const size_t ZERO_BYTES = 21120000;
    int*   cur_up  = (int*)((char*)d_ws + 21120000);
    int*   cur_dn  = (int*)((char*)d_ws + 21200000);
    int*   es_up   = (int*)((char*)d_ws + 21280000);
    int*   es_dn   = (int*)((char*)d_ws + 22080000);
    u16*   fbase   = (u16*)((char*)d_ws + 22880000);
    u16*   canon   = (u16*)((char*)d_ws + 23240448);
    int*   flag    = (int*)((char*)d_ws + 34164000);
    if (ws_size < 34164004ULL) return;

    u16* f_m1u = fbase;              // 32768 (K=256)
    u16* f_m2u = fbase + 32768;      // 16384 (K=128)
    u16* f_p1u = fbase + 49152;      // 16384
    u16* f_m1d = fbase + 65536;      // 32768
    u16* f_m2d = fbase + 98304;      // 16384
    u16* f_p1d = fbase + 114688;     // 16384
    u16* f_u1  = fbase + 131072;     // 32768
    u16* f_u2  = fbase + 163840;     // 16384

    // canonical tensor pointers
    u16* cfeat = canon;
    u16* cpos  = canon + 5120000;
    u16* cdgu  = canon + 5240000;
    u16* cdgd  = canon + 5260000;
    u16* cm1u  = canon + 5280000;
    u16* cbm1u = canon + 5312896;
    u16* cm2u  = canon + 5313024;
    u16* cbm2u = canon + 5329408;
    u16* cp1u  = canon + 5329536;
    u16* cbp1u = canon + 5345920;
    u16* cp2u  = canon + 5346048;
    u16* cbp2u = canon + 5346176;
    u16* cm1d  = canon + 5346184;
    u16* cbm1d = canon + 5379080;
    u16* cm2d  = canon + 5379208;
    u16* cbm2d = canon + 5395592;
    u16* cp1d  = canon + 5395720;
    u16* cbp1d = canon + 5412104;
    u16* cp2d  = canon + 5412232;
    u16* cbp2d = canon + 5412360;
    u16* cu1   = canon + 5412368;
    u16* cbu1  = canon + 5445136;
    u16* cu2   = canon + 5445264;
    u16* cbu2  = canon + 5461648;

    hipMemsetAsync(d_ws, 0, ZERO_BYTES, stream);

    detect_kernel<<<1, 256, 0, stream>>>((const u16*)d_in[0], flag);

    P24 ptrs;
    ptrs.p[0] = d_in[0];  ptrs.p[1] = d_in[1];  ptrs.p[2] = d_in[4];  ptrs.p[3] = d_in[5];
    ptrs.p[4] = d_in[6];  ptrs.p[5] = d_in[7];  ptrs.p[6] = d_in[8];  ptrs.p[7] = d_in[9];
    ptrs.p[8] = d_in[10]; ptrs.p[9] = d_in[11]; ptrs.p[10] = d_in[12]; ptrs.p[11] = d_in[13];
    ptrs.p[12] = d_in[14]; ptrs.p[13] = d_in[15]; ptrs.p[14] = d_in[16]; ptrs.p[15] = d_in[17];
    ptrs.p[16] = d_in[18]; ptrs.p[17] = d_in[19]; ptrs.p[18] = d_in[20]; ptrs.p[19] = d_in[21];
    ptrs.p[20] = d_in[22]; ptrs.p[21] = d_in[23]; ptrs.p[22] = d_in[24]; ptrs.p[23] = d_in[25];
    canon_kernel<<<(CTOT + 255) / 256, 256, 0, stream>>>(ptrs, flag, canon);

    make_frag<<<128, 256, 0, stream>>>(cm1u, f_m1u);
    make_frag<<<64,  256, 0, stream>>>(cm2u, f_m2u);
    make_frag<<<64,  256, 0, stream>>>(cp1u, f_p1u);
    make_frag<<<128, 256, 0, stream>>>(cm1d, f_m1d);
    make_frag<<<64,  256, 0, stream>>>(cm2d, f_m2d);
    make_frag<<<64,  256, 0, stream>>>(cp1d, f_p1d);
    make_frag<<<128, 256, 0, stream>>>(cu1,  f_u1);
    make_frag<<<64,  256, 0, stream>>>(cu2,  f_u2);

    const int* ei_up = (const int*)d_in[2];
    const int* ei_dn = (const int*)d_in[3];

    // CSR build (dst-sorted edge permutation) per neighborhood
    count_kernel<<<(EE + 255) / 256, 256, 0, stream>>>(ei_up, cnt_up);
    count_kernel<<<(EE + 255) / 256, 256, 0, stream>>>(ei_dn, cnt_dn);
    scan_kernel<<<1, 1024, 0, stream>>>(cnt_up, cur_up);
    scan_kernel<<<1, 1024, 0, stream>>>(cnt_dn, cur_dn);
    scatter_kernel<<<(EE + 255) / 256, 256, 0, stream>>>(ei_up, cur_up, es_up);
    scatter_kernel<<<(EE + 255) / 256, 256, 0, stream>>>(ei_dn, cur_dn, es_dn);

    edge_kernel<<<BB * EBLK, 256, 0, stream>>>(
        cfeat, cpos, ei_up, es_up, cdgu,
        f_m1u, cm1u + 256 * 128, cbm1u,
        f_m2u, cbm2u,
        f_p1u, cbp1u, cp2u, cbp2u,
        msg_acc, pos_acc);
    edge_kernel<<<BB * EBLK, 256, 0, stream>>>(
        cfeat, cpos, ei_dn, es_dn, cdgd,
        f_m1d, cm1d + 256 * 128, cbm1d,
        f_m2d, cbm2d,
        f_p1d, cbp1d, cp2d, cbp2d,
        msg_acc, pos_acc);

    update_kernel<<<625, 256, 0, stream>>>(
        cfeat, d_in[0], msg_acc,
        f_u1, cbu1, f_u2, cbu2, d_out, flag);

    pos_out_kernel<<<469, 256, 0, stream>>>(d_in[1], cpos, pos_acc, d_out, flag);
}

// Round 5
// 527.218 us; speedup vs baseline: 6.0701x; 1.1657x over previous
//
#include <hip/hip_runtime.h>

#define BB 2
#define NN 20000
#define HH 128
#define EE 200000
#define EBLK 3125   // EE / 64
#define NBLK 79     // ceil(NN/256)

typedef unsigned short u16;
typedef __attribute__((ext_vector_type(4))) float f32x4;
typedef __bf16 bf16x8 __attribute__((ext_vector_type(8)));

#define MFMA(a, b, c) __builtin_amdgcn_mfma_f32_16x16x32_bf16((a), (b), (c), 0, 0, 0)

__device__ __forceinline__ float bf2f(u16 u) {
    union { unsigned int i; float f; } v; v.i = ((unsigned int)u) << 16; return v.f;
}
// native RTNE via v_cvt_pk_bf16_f32 on gfx950
__device__ __forceinline__ u16 f2bf(float f) {
    union { __bf16 h; u16 u; } v; v.h = (__bf16)f; return v.u;
}
__device__ __forceinline__ float silu_f(float z) { return z / (1.f + __expf(-z)); }

// ---------------- dtype detection ----------------
__global__ void detect_kernel(const u16* __restrict__ f, int* __restrict__ flag) {
    int tid = threadIdx.x;
    u16 v = f[tid * 2];
    int e = (v >> 7) & 0xFF;
    int ok = (e >= 101 && e <= 143) ? 1 : 0;
    __shared__ int cnt;
    if (tid == 0) cnt = 0;
    __syncthreads();
    atomicAdd(&cnt, ok);
    __syncthreads();
    if (tid == 0) *flag = (cnt < 200) ? 1 : 0;   // 1 => inputs are float32
}

// ---------------- canonicalize all float inputs to bf16 in ws ----------------
#define CTOT 5461776
struct P24 { const void* p[24]; };

__global__ __launch_bounds__(256) void canon_kernel(P24 ptrs, const int* __restrict__ flag,
                                                    u16* __restrict__ canon) {
    static const int off[25] = {
        0, 5120000, 5240000, 5260000, 5280000, 5312896, 5313024, 5329408,
        5329536, 5345920, 5346048, 5346176, 5346184, 5379080, 5379208, 5395592,
        5395720, 5412104, 5412232, 5412360, 5412368, 5445136, 5445264, 5461648,
        5461776 };
    static const int rsz[24] = {
        5120000, 120000, 20000, 20000,
        32896, 128, 16384, 128, 16384, 128, 128, 1,
        32896, 128, 16384, 128, 16384, 128, 128, 1,
        32768, 128, 16384, 128 };
    int i = blockIdx.x * 256 + threadIdx.x;
    if (i >= CTOT) return;
    int t = 0;
#pragma unroll 1
    while (i >= off[t + 1]) ++t;
    int j = i - off[t];
    u16 v;
    if (j >= rsz[t]) v = 0;
    else if (*flag) v = f2bf(((const float*)ptrs.p[t])[j]);
    else v = ((const u16*)ptrs.p[t])[j];
    canon[i] = v;
}

// ---------------- weight fragment permutation ----------------
__global__ void make_frag(const u16* __restrict__ W, u16* __restrict__ F) {
    int tid = blockIdx.x * 256 + threadIdx.x;
    int j = tid & 7, lane = (tid >> 3) & 63, nt = (tid >> 9) & 7, kt = tid >> 12;
    int k = kt * 32 + ((lane >> 4) * 8) + j;
    int n = nt * 16 + (lane & 15);
    F[tid] = W[k * 128 + n];
}

// ---------------- CSR build: count -> multiblock scan -> cursor scatter -----
__global__ void count2_kernel(const int* __restrict__ eu, const int* __restrict__ ed,
                              int* __restrict__ cu, int* __restrict__ cd) {
    int e = blockIdx.x * 256 + threadIdx.x;
    if (e < EE) atomicAdd(&cu[eu[EE + e]], 1);
    else { e -= EE; if (e < EE) atomicAdd(&cd[ed[EE + e]], 1); }
}

struct SP { const int* cnt[2]; int* cur[2]; int* bsum[2]; };

__global__ __launch_bounds__(256) void scan1_kernel(SP p) {
    int half = blockIdx.x / NBLK;
    int b = blockIdx.x - half * NBLK;
    int t = threadIdx.x;
    int i = b * 256 + t;
    __shared__ int buf[256];
    int v = (i < NN) ? p.cnt[half][i] : 0;
    buf[t] = v;
    __syncthreads();
    for (int s = 1; s < 256; s <<= 1) {
        int x = (t >= s) ? buf[t - s] : 0;
        __syncthreads();
        buf[t] += x;
        __syncthreads();
    }
    if (i < NN) p.cur[half][i] = buf[t] - v;   // exclusive within block
    if (t == 255) p.bsum[half][b] = buf[255];
}

__global__ __launch_bounds__(256) void scan2_kernel(int* __restrict__ bu, int* __restrict__ bd) {
    __shared__ int buf[2][128];
    int half = threadIdx.x >> 7, t = threadIdx.x & 127;
    int* bs = half ? bd : bu;
    int v = (t < NBLK) ? bs[t] : 0;
    buf[half][t] = v;
    __syncthreads();
    for (int s = 1; s < 128; s <<= 1) {
        int x = (t >= s) ? buf[half][t - s] : 0;
        __syncthreads();
        buf[half][t] += x;
        __syncthreads();
    }
    if (t < NBLK) bs[t] = buf[half][t] - v;    // exclusive block offsets
}

__global__ void scan3_kernel(int* __restrict__ cu, const int* __restrict__ bu,
                             int* __restrict__ cd, const int* __restrict__ bd) {
    int i = blockIdx.x * 256 + threadIdx.x;
    if (i < NN) cu[i] += bu[i >> 8];
    else { i -= NN; if (i < NN) cd[i] += bd[i >> 8]; }
}

__global__ void scatter2_kernel(const int* __restrict__ eu, const int* __restrict__ ed,
                                int* __restrict__ cu, int* __restrict__ cd,
                                int* __restrict__ su, int* __restrict__ sd) {
    int e = blockIdx.x * 256 + threadIdx.x;
    if (e < EE) { int p = atomicAdd(&cu[eu[EE + e]], 1); su[p] = e; }
    else { e -= EE; if (e < EE) { int p = atomicAdd(&cd[ed[EE + e]], 1); sd[p] = e; } }
}

// ---------------- edge kernel: both neighborhoods in one grid ----------------
struct EP {
    const int* eidx; const int* es; const u16* deg;
    const u16* fW1; const u16* w1last; const u16* bias1;
    const u16* fW2; const u16* bias2;
    const u16* fP1; const u16* biasp1;
    const u16* wp2; const u16* biasp2;
};

__global__ __launch_bounds__(256, 4) void edge_kernel(
    const u16* __restrict__ feat, const u16* __restrict__ posit,
    EP up, EP dn,
    float* __restrict__ msg_acc, float* __restrict__ pos_acc)
{
    const int tid = threadIdx.x;
    const int lane = tid & 63;
    const int wv = tid >> 6;
    const int half = blockIdx.x / (BB * EBLK);
    const int rem = blockIdx.x - half * (BB * EBLK);
    const int bb = rem / EBLK;                 // batch
    const int s0 = (rem - bb * EBLK) * 64;     // slot base
    const EP P = half ? dn : up;

    __shared__ u16 sX[64][136];   // h_src -> msg-hidden -> pos-hidden
    __shared__ u16 sY[64][136];   // h_dst -> messages
    __shared__ float sRel[64][3];
    __shared__ float sDist[64];
    __shared__ float sInv[64];
    __shared__ int sSrc[64], sDst[64];

    if (tid < 64) {
        int e = P.es[s0 + tid];
        int s = P.eidx[e];
        int d = P.eidx[EE + e];
        sSrc[tid] = s; sDst[tid] = d;
        sInv[tid] = 1.f / fmaxf(bf2f(P.deg[d]), 1.f);
        const u16* ps = posit + ((size_t)bb * NN + s) * 3;
        const u16* pd = posit + ((size_t)bb * NN + d) * 3;
        float dx = bf2f(ps[0]) - bf2f(pd[0]);
        float dy = bf2f(ps[1]) - bf2f(pd[1]);
        float dz = bf2f(ps[2]) - bf2f(pd[2]);
        sRel[tid][0] = dx; sRel[tid][1] = dy; sRel[tid][2] = dz;
        sDist[tid] = sqrtf(dx * dx + dy * dy + dz * dz);
    }
    __syncthreads();   // B0

    // gather h_src -> sX, h_dst -> sY (dst rows repeat -> L1 hits)
    {
        const int r = tid >> 2, part = tid & 3;
        const uint4* fs = (const uint4*)(feat + ((size_t)bb * NN + sSrc[r]) * HH);
        const uint4* fd = (const uint4*)(feat + ((size_t)bb * NN + sDst[r]) * HH);
        uint4* as = (uint4*)&sX[r][part * 32];
        uint4* ad = (uint4*)&sY[r][part * 32];
#pragma unroll
        for (int i = 0; i < 4; ++i) { as[i] = fs[part * 4 + i]; ad[i] = fd[part * 4 + i]; }
    }
    __syncthreads();   // B1

    const int nt0 = wv * 2;
    const int mrow = lane & 15;
    const int kq = (lane >> 4) * 8;
    const int crow = (lane >> 4) * 4;
    const int ccol = lane & 15;

    f32x4 acc[4][2];
#pragma unroll
    for (int mt = 0; mt < 4; ++mt) {
        acc[mt][0] = (f32x4){0.f, 0.f, 0.f, 0.f};
        acc[mt][1] = (f32x4){0.f, 0.f, 0.f, 0.f};
    }

    // ----- msg layer 1 : [h_src | h_dst] @ W1[0:256]  (K=256) -----
#pragma unroll
    for (int kt = 0; kt < 8; ++kt) {
        const u16* Xb = (kt < 4) ? &sX[0][0] : &sY[0][0];
        const int kk = (kt & 3) * 32 + kq;
        bf16x8 bw0 = *(const bf16x8*)(P.fW1 + (size_t)(((kt * 8 + nt0) * 64 + lane) * 8));
        bf16x8 bw1 = *(const bf16x8*)(P.fW1 + (size_t)(((kt * 8 + nt0 + 1) * 64 + lane) * 8));
#pragma unroll
        for (int mt = 0; mt < 4; ++mt) {
            bf16x8 a = *(const bf16x8*)(Xb + (mt * 16 + mrow) * 136 + kk);
            acc[mt][0] = MFMA(a, bw0, acc[mt][0]);
            acc[mt][1] = MFMA(a, bw1, acc[mt][1]);
        }
    }
    __syncthreads();   // B2: all L1 reads of sX/sY done

    // epilogue: + dist*W1[256] + b1, silu -> sX
#pragma unroll
    for (int mt = 0; mt < 4; ++mt) {
#pragma unroll
        for (int n2 = 0; n2 < 2; ++n2) {
            const int col = (nt0 + n2) * 16 + ccol;
            const float wl = bf2f(P.w1last[col]);
            const float bb2 = bf2f(P.bias1[col]);
#pragma unroll
            for (int r = 0; r < 4; ++r) {
                const int row = mt * 16 + crow + r;
                float z = fmaf(sDist[row], wl, acc[mt][n2][r]) + bb2;
                sX[row][col] = f2bf(silu_f(z));
            }
        }
    }
    __syncthreads();   // B3

    // ----- msg layer 2 : sX @ W2 + b2 = messages -> sY (K=128) -----
#pragma unroll
    for (int mt = 0; mt < 4; ++mt) {
        acc[mt][0] = (f32x4){0.f, 0.f, 0.f, 0.f};
        acc[mt][1] = (f32x4){0.f, 0.f, 0.f, 0.f};
    }
#pragma unroll
    for (int kt = 0; kt < 4; ++kt) {
        const int kk = kt * 32 + kq;
        bf16x8 bw0 = *(const bf16x8*)(P.fW2 + (size_t)(((kt * 8 + nt0) * 64 + lane) * 8));
        bf16x8 bw1 = *(const bf16x8*)(P.fW2 + (size_t)(((kt * 8 + nt0 + 1) * 64 + lane) * 8));
#pragma unroll
        for (int mt = 0; mt < 4; ++mt) {
            bf16x8 a = *(const bf16x8*)(&sX[0][0] + (mt * 16 + mrow) * 136 + kk);
            acc[mt][0] = MFMA(a, bw0, acc[mt][0]);
            acc[mt][1] = MFMA(a, bw1, acc[mt][1]);
        }
    }
#pragma unroll
    for (int mt = 0; mt < 4; ++mt) {
#pragma unroll
        for (int n2 = 0; n2 < 2; ++n2) {
            const int col = (nt0 + n2) * 16 + ccol;
            const float bb2 = bf2f(P.bias2[col]);
#pragma unroll
            for (int r = 0; r < 4; ++r) {
                const int row = mt * 16 + crow + r;
                sY[row][col] = f2bf(acc[mt][n2][r] + bb2);
            }
        }
    }
    __syncthreads();   // B4: messages visible; all L2 reads of sX done

    // ----- pos layer 1 : silu(messages @ P1 + bp1) -> sX (K=128) -----
#pragma unroll
    for (int mt = 0; mt < 4; ++mt) {
        acc[mt][0] = (f32x4){0.f, 0.f, 0.f, 0.f};
        acc[mt][1] = (f32x4){0.f, 0.f, 0.f, 0.f};
    }
#pragma unroll
    for (int kt = 0; kt < 4; ++kt) {
        const int kk = kt * 32 + kq;
        bf16x8 bw0 = *(const bf16x8*)(P.fP1 + (size_t)(((kt * 8 + nt0) * 64 + lane) * 8));
        bf16x8 bw1 = *(const bf16x8*)(P.fP1 + (size_t)(((kt * 8 + nt0 + 1) * 64 + lane) * 8));
#pragma unroll
        for (int mt = 0; mt < 4; ++mt) {
            bf16x8 a = *(const bf16x8*)(&sY[0][0] + (mt * 16 + mrow) * 136 + kk);
            acc[mt][0] = MFMA(a, bw0, acc[mt][0]);
            acc[mt][1] = MFMA(a, bw1, acc[mt][1]);
        }
    }

    // segment-reduced scatter of messages (rows sorted by dst)
    {
        const int col = tid & 127;
        const int r0 = (tid >> 7) * 32;
        float accv = 0.f;
        int dprev = sDst[r0];
        float invprev = sInv[r0];
#pragma unroll 1
        for (int r = r0; r < r0 + 32; ++r) {
            int dcur = sDst[r];
            if (dcur != dprev) {
                unsafeAtomicAdd(&msg_acc[((size_t)bb * NN + dprev) * HH + col], accv * invprev);
                accv = 0.f; dprev = dcur; invprev = sInv[r];
            }
            accv += bf2f(sY[r][col]);
        }
        unsafeAtomicAdd(&msg_acc[((size_t)bb * NN + dprev) * HH + col], accv * invprev);
    }

    // pos1 epilogue -> sX
#pragma unroll
    for (int mt = 0; mt < 4; ++mt) {
#pragma unroll
        for (int n2 = 0; n2 < 2; ++n2) {
            const int col = (nt0 + n2) * 16 + ccol;
            const float bb2 = bf2f(P.biasp1[col]);
#pragma unroll
            for (int r = 0; r < 4; ++r) {
                const int row = mt * 16 + crow + r;
                sX[row][col] = f2bf(silu_f(acc[mt][n2][r] + bb2));
            }
        }
    }
    __syncthreads();   // B5

    // ----- pos layer 2 : tanh(hidden @ p2 + bp2) ; scatter wgt*rel_pos -----
    {
        const int r = tid >> 2, q = tid & 3;
        const unsigned int* t32 = (const unsigned int*)&sX[r][q * 32];
        const unsigned int* w32 = (const unsigned int*)(P.wp2 + q * 32);
        float p = 0.f;
#pragma unroll
        for (int k = 0; k < 16; ++k) {
            unsigned int a = t32[k], b = w32[k];
            union { unsigned int i; float f; } al, ah, bl, bh;
            al.i = a << 16; ah.i = a & 0xffff0000u;
            bl.i = b << 16; bh.i = b & 0xffff0000u;
            p = fmaf(al.f, bl.f, p);
            p = fmaf(ah.f, bh.f, p);
        }
        p += __shfl_xor(p, 1);
        p += __shfl_xor(p, 2);
        if (q == 0) {
            float wgt = tanhf(p + bf2f(P.biasp2[0]));
            const size_t pb = ((size_t)bb * NN + sDst[r]) * 3;
            unsafeAtomicAdd(&pos_acc[pb + 0], wgt * sRel[r][0]);
            unsafeAtomicAdd(&pos_acc[pb + 1], wgt * sRel[r][1]);
            unsafeAtomicAdd(&pos_acc[pb + 2], wgt * sRel[r][2]);
        }
    }
}

__global__ __launch_bounds__(256) void update_kernel(
    const u16* __restrict__ feat, const void* __restrict__ rawfeat,
    const float* __restrict__ magg,
    const u16* __restrict__ fU1, const u16* __restrict__ bu1,
    const u16* __restrict__ fU2, const u16* __restrict__ bu2,
    void* __restrict__ outp, const int* __restrict__ flag)
{
    const int tid = threadIdx.x;
    const int lane = tid & 63;
    const int wv = tid >> 6;
    const int row0 = blockIdx.x * 64;   // node-instance rows
    const int isf = *flag;

    __shared__ u16 sA[64][136];   // features (bf16)
    __shared__ u16 sB[64][136];   // msg_acc (bf16)
    __shared__ u16 sY[64][136];   // hidden

    {
        const uint4* src = (const uint4*)(feat + (size_t)row0 * HH);
        for (int i = tid; i < 1024; i += 256) {
            int r = i >> 4, c = i & 15;
            *(uint4*)&sA[r][c * 8] = src[i];
        }
        const float4* am = (const float4*)(magg) + (size_t)row0 * 32;
        for (int i = tid; i < 2048; i += 256) {
            int r = i >> 5;
            float4 v = am[i];
            int c = (i & 31) * 4;
            sB[r][c + 0] = f2bf(v.x);
            sB[r][c + 1] = f2bf(v.y);
            sB[r][c + 2] = f2bf(v.z);
            sB[r][c + 3] = f2bf(v.w);
        }
    }
    __syncthreads();

    const int nt0 = wv * 2;
    const int mrow = lane & 15;
    const int kq = (lane >> 4) * 8;
    const int crow = (lane >> 4) * 4;
    const int ccol = lane & 15;

    f32x4 acc[4][2];
#pragma unroll
    for (int mt = 0; mt < 4; ++mt) {
        acc[mt][0] = (f32x4){0.f, 0.f, 0.f, 0.f};
        acc[mt][1] = (f32x4){0.f, 0.f, 0.f, 0.f};
    }
    // layer 1: [features | msg_acc] @ w_upd1 (K=256), silu
#pragma unroll
    for (int kt = 0; kt < 8; ++kt) {
        const u16* Xb = (kt < 4) ? &sA[0][0] : &sB[0][0];
        const int kk = (kt & 3) * 32 + kq;
        bf16x8 bw0 = *(const bf16x8*)(fU1 + (size_t)(((kt * 8 + nt0) * 64 + lane) * 8));
        bf16x8 bw1 = *(const bf16x8*)(fU1 + (size_t)(((kt * 8 + nt0 + 1) * 64 + lane) * 8));
#pragma unroll
        for (int mt = 0; mt < 4; ++mt) {
            bf16x8 a = *(const bf16x8*)(Xb + (mt * 16 + mrow) * 136 + kk);
            acc[mt][0] = MFMA(a, bw0, acc[mt][0]);
            acc[mt][1] = MFMA(a, bw1, acc[mt][1]);
        }
    }
#pragma unroll
    for (int mt = 0; mt < 4; ++mt) {
#pragma unroll
        for (int n2 = 0; n2 < 2; ++n2) {
            const int col = (nt0 + n2) * 16 + ccol;
            const float bb = bf2f(bu1[col]);
#pragma unroll
            for (int r = 0; r < 4; ++r) {
                const int row = mt * 16 + crow + r;
                sY[row][col] = f2bf(silu_f(acc[mt][n2][r] + bb));
            }
        }
    }
    __syncthreads();

    // layer 2 + residual -> out
#pragma unroll
    for (int mt = 0; mt < 4; ++mt) {
        acc[mt][0] = (f32x4){0.f, 0.f, 0.f, 0.f};
        acc[mt][1] = (f32x4){0.f, 0.f, 0.f, 0.f};
    }
#pragma unroll
    for (int kt = 0; kt < 4; ++kt) {
        const int kk = kt * 32 + kq;
        bf16x8 bw0 = *(const bf16x8*)(fU2 + (size_t)(((kt * 8 + nt0) * 64 + lane) * 8));
        bf16x8 bw1 = *(const bf16x8*)(fU2 + (size_t)(((kt * 8 + nt0 + 1) * 64 + lane) * 8));
#pragma unroll
        for (int mt = 0; mt < 4; ++mt) {
            bf16x8 a = *(const bf16x8*)(&sY[0][0] + (mt * 16 + mrow) * 136 + kk);
            acc[mt][0] = MFMA(a, bw0, acc[mt][0]);
            acc[mt][1] = MFMA(a, bw1, acc[mt][1]);
        }
    }
#pragma unroll
    for (int mt = 0; mt < 4; ++mt) {
#pragma unroll
        for (int n2 = 0; n2 < 2; ++n2) {
            const int col = (nt0 + n2) * 16 + ccol;
            const float bb = bf2f(bu2[col]);
#pragma unroll
            for (int r = 0; r < 4; ++r) {
                const int row = mt * 16 + crow + r;
                const size_t idx = (size_t)(row0 + row) * HH + col;
                if (isf) {
                    float base = ((const float*)rawfeat)[idx];
                    ((float*)outp)[idx] = acc[mt][n2][r] + bb + base;
                } else {
                    float base = bf2f(sA[row][col]);
                    ((u16*)outp)[idx] = f2bf(acc[mt][n2][r] + bb + base);
                }
            }
        }
    }
}

__global__ void pos_out_kernel(const void* __restrict__ rawpos, const u16* __restrict__ cpos,
                               const float* __restrict__ pacc, void* __restrict__ outp,
                               const int* __restrict__ flag)
{
    int i = blockIdx.x * 256 + threadIdx.x;
    if (i >= BB * NN * 3) return;
    if (*flag) {
        float base = ((const float*)rawpos)[i];
        ((float*)outp)[5120000 + i] = base + 0.5f * pacc[i];
    } else {
        float base = bf2f(cpos[i]);
        ((u16*)outp)[5120000 + i] = f2bf(base + 0.5f * pacc[i]);
    }
}

extern "C" void kernel_launch(void* const* d_in, const int* in_sizes, int n_in,
                              void* d_out, int out_size, void* d_ws, size_t ws_size,
                              hipStream_t stream)
{
    // workspace layout (bytes):
    //   [0,          20,480,000)  msg_acc f32 (memset 0)
    //   [20,480,000, 20,960,000)  pos_acc f32 (memset 0)
    //   [20,960,000, 21,040,000)  cnt_up  (memset 0)
    //   [21,040,000, 21,120,000)  cnt_dn  (memset 0)
    //   [21,120,000, 21,200,000)  cur_up
    //   [21,200,000, 21,280,000)  cur_dn
    //   [21,280,000, 21,280,400)  bsum_up (79 ints)
    //   [21,280,400, 21,280,800)  bsum_dn
    //   [21,280,800, 22,080,800)  es_up (sorted edge ids)
    //   [22,080,800, 22,880,800)  es_dn
    //   [22,880,800, 23,241,248)  weight fragments (180,224 u16)
    //   [23,241,248, 34,164,800)  canonical bf16 inputs (5,461,776 u16)
    //   [34,164,800, +4)          dtype flag
    float* msg_acc = (float*)d_ws;
    float* pos_acc = (float*)((char*)d_ws + 20480000);
    int*   cnt_up  = (int*)((char*)d_ws + 20960000);
    int*   cnt_dn  = (int*)((char*)d_ws + 21040000);
    const size_t ZERO_BYTES = 21120000;
    int*   cur_up  = (int*)((char*)d_ws + 21120000);
    int*   cur_dn  = (int*)((char*)d_ws + 21200000);
    int*   bsum_up = (int*)((char*)d_ws + 21280000);
    int*   bsum_dn = (int*)((char*)d_ws + 21280400);
    int*   es_up   = (int*)((char*)d_ws + 21280800);
    int*   es_dn   = (int*)((char*)d_ws + 22080800);
    u16*   fbase   = (u16*)((char*)d_ws + 22880800);
    u16*   canon   = (u16*)((char*)d_ws + 23241248);
    int*   flag    = (int*)((char*)d_ws + 34164800);
    if (ws_size < 34164804ULL) return;

    u16* f_m1u = fbase;              // 32768 (K=256)
    u16* f_m2u = fbase + 32768;      // 16384 (K=128)
    u16* f_p1u = fbase + 49152;      // 16384
    u16* f_m1d = fbase + 65536;      // 32768
    u16* f_m2d = fbase + 98304;      // 16384
    u16* f_p1d = fbase + 114688;     // 16384
    u16* f_u1  = fbase + 131072;     // 32768
    u16* f_u2  = fbase + 163840;     // 16384

    // canonical tensor pointers
    u16* cfeat = canon;
    u16* cpos  = canon + 5120000;
    u16* cdgu  = canon + 5240000;
    u16* cdgd  = canon + 5260000;
    u16* cm1u  = canon + 5280000;
    u16* cbm1u = canon + 5312896;
    u16* cm2u  = canon + 5313024;
    u16* cbm2u = canon + 5329408;
    u16* cp1u  = canon + 5329536;
    u16* cbp1u = canon + 5345920;
    u16* cp2u  = canon + 5346048;
    u16* cbp2u = canon + 5346176;
    u16* cm1d  = canon + 5346184;
    u16* cbm1d = canon + 5379080;
    u16* cm2d  = canon + 5379208;
    u16* cbm2d = canon + 5395592;
    u16* cp1d  = canon + 5395720;
    u16* cbp1d = canon + 5412104;
    u16* cp2d  = canon + 5412232;
    u16* cbp2d = canon + 5412360;
    u16* cu1   = canon + 5412368;
    u16* cbu1  = canon + 5445136;
    u16* cu2   = canon + 5445264;
    u16* cbu2  = canon + 5461648;

    hipMemsetAsync(d_ws, 0, ZERO_BYTES, stream);

    detect_kernel<<<1, 256, 0, stream>>>((const u16*)d_in[0], flag);

    P24 ptrs;
    ptrs.p[0] = d_in[0];  ptrs.p[1] = d_in[1];  ptrs.p[2] = d_in[4];  ptrs.p[3] = d_in[5];
    ptrs.p[4] = d_in[6];  ptrs.p[5] = d_in[7];  ptrs.p[6] = d_in[8];  ptrs.p[7] = d_in[9];
    ptrs.p[8] = d_in[10]; ptrs.p[9] = d_in[11]; ptrs.p[10] = d_in[12]; ptrs.p[11] = d_in[13];
    ptrs.p[12] = d_in[14]; ptrs.p[13] = d_in[15]; ptrs.p[14] = d_in[16]; ptrs.p[15] = d_in[17];
    ptrs.p[16] = d_in[18]; ptrs.p[17] = d_in[19]; ptrs.p[18] = d_in[20]; ptrs.p[19] = d_in[21];
    ptrs.p[20] = d_in[22]; ptrs.p[21] = d_in[23]; ptrs.p[22] = d_in[24]; ptrs.p[23] = d_in[25];
    canon_kernel<<<(CTOT + 255) / 256, 256, 0, stream>>>(ptrs, flag, canon);

    make_frag<<<128, 256, 0, stream>>>(cm1u, f_m1u);
    make_frag<<<64,  256, 0, stream>>>(cm2u, f_m2u);
    make_frag<<<64,  256, 0, stream>>>(cp1u, f_p1u);
    make_frag<<<128, 256, 0, stream>>>(cm1d, f_m1d);
    make_frag<<<64,  256, 0, stream>>>(cm2d, f_m2d);
    make_frag<<<64,  256, 0, stream>>>(cp1d, f_p1d);
    make_frag<<<128, 256, 0, stream>>>(cu1,  f_u1);
    make_frag<<<64,  256, 0, stream>>>(cu2,  f_u2);

    const int* ei_up = (const int*)d_in[2];
    const int* ei_dn = (const int*)d_in[3];

    // CSR build: count -> multiblock scan -> cursor scatter (both neighborhoods)
    count2_kernel<<<(2 * EE + 255) / 256, 256, 0, stream>>>(ei_up, ei_dn, cnt_up, cnt_dn);
    SP sp;
    sp.cnt[0] = cnt_up; sp.cnt[1] = cnt_dn;
    sp.cur[0] = cur_up; sp.cur[1] = cur_dn;
    sp.bsum[0] = bsum_up; sp.bsum[1] = bsum_dn;
    scan1_kernel<<<2 * NBLK, 256, 0, stream>>>(sp);
    scan2_kernel<<<1, 256, 0, stream>>>(bsum_up, bsum_dn);
    scan3_kernel<<<(2 * NN + 255) / 256, 256, 0, stream>>>(cur_up, bsum_up, cur_dn, bsum_dn);
    scatter2_kernel<<<(2 * EE + 255) / 256, 256, 0, stream>>>(ei_up, ei_dn, cur_up, cur_dn,
                                                              es_up, es_dn);

    EP up, dn;
    up.eidx = ei_up; up.es = es_up; up.deg = cdgu;
    up.fW1 = f_m1u; up.w1last = cm1u + 256 * 128; up.bias1 = cbm1u;
    up.fW2 = f_m2u; up.bias2 = cbm2u;
    up.fP1 = f_p1u; up.biasp1 = cbp1u;
    up.wp2 = cp2u;  up.biasp2 = cbp2u;
    dn.eidx = ei_dn; dn.es = es_dn; dn.deg = cdgd;
    dn.fW1 = f_m1d; dn.w1last = cm1d + 256 * 128; dn.bias1 = cbm1d;
    dn.fW2 = f_m2d; dn.bias2 = cbm2d;
    dn.fP1 = f_p1d; dn.biasp1 = cbp1d;
    dn.wp2 = cp2d;  dn.biasp2 = cbp2d;

    edge_kernel<<<2 * BB * EBLK, 256, 0, stream>>>(cfeat, cpos, up, dn, msg_acc, pos_acc);

    update_kernel<<<625, 256, 0, stream>>>(
        cfeat, d_in[0], msg_acc,
        f_u1, cbu1, f_u2, cbu2, d_out, flag);

    pos_out_kernel<<<469, 256, 0, stream>>>(d_in[1], cpos, pos_acc, d_out, flag);
}

// Round 6
// 525.066 us; speedup vs baseline: 6.0949x; 1.0041x over previous
//
#include <hip/hip_runtime.h>

#define BB 2
#define NN 20000
#define HH 128
#define EE 200000
#define EBLK 3125   // EE / 64
#define NBLK 79     // ceil(NN/256)

typedef unsigned short u16;
typedef __attribute__((ext_vector_type(4))) float f32x4;
typedef __bf16 bf16x8 __attribute__((ext_vector_type(8)));

#define MFMA(a, b, c) __builtin_amdgcn_mfma_f32_16x16x32_bf16((a), (b), (c), 0, 0, 0)

__device__ __forceinline__ float bf2f(u16 u) {
    union { unsigned int i; float f; } v; v.i = ((unsigned int)u) << 16; return v.f;
}
// native RTNE via v_cvt_pk_bf16_f32 on gfx950
__device__ __forceinline__ u16 f2bf(float f) {
    union { __bf16 h; u16 u; } v; v.h = (__bf16)f; return v.u;
}
__device__ __forceinline__ float silu_f(float z) { return z / (1.f + __expf(-z)); }

// ---------------- dtype detection ----------------
__global__ void detect_kernel(const u16* __restrict__ f, int* __restrict__ flag) {
    int tid = threadIdx.x;
    u16 v = f[tid * 2];
    int e = (v >> 7) & 0xFF;
    int ok = (e >= 101 && e <= 143) ? 1 : 0;
    __shared__ int cnt;
    if (tid == 0) cnt = 0;
    __syncthreads();
    atomicAdd(&cnt, ok);
    __syncthreads();
    if (tid == 0) *flag = (cnt < 200) ? 1 : 0;   // 1 => inputs are float32
}

// ---------------- canonicalize all float inputs to bf16 in ws ----------------
#define CTOT 5461776
struct P24 { const void* p[24]; };

__global__ __launch_bounds__(256) void canon_kernel(P24 ptrs, const int* __restrict__ flag,
                                                    u16* __restrict__ canon) {
    static const int off[25] = {
        0, 5120000, 5240000, 5260000, 5280000, 5312896, 5313024, 5329408,
        5329536, 5345920, 5346048, 5346176, 5346184, 5379080, 5379208, 5395592,
        5395720, 5412104, 5412232, 5412360, 5412368, 5445136, 5445264, 5461648,
        5461776 };
    static const int rsz[24] = {
        5120000, 120000, 20000, 20000,
        32896, 128, 16384, 128, 16384, 128, 128, 1,
        32896, 128, 16384, 128, 16384, 128, 128, 1,
        32768, 128, 16384, 128 };
    int i = blockIdx.x * 256 + threadIdx.x;
    if (i >= CTOT) return;
    int t = 0;
#pragma unroll 1
    while (i >= off[t + 1]) ++t;
    int j = i - off[t];
    u16 v;
    if (j >= rsz[t]) v = 0;
    else if (*flag) v = f2bf(((const float*)ptrs.p[t])[j]);
    else v = ((const u16*)ptrs.p[t])[j];
    canon[i] = v;
}

// ---------------- weight fragment permutation (all 8 in one launch) --------
// F[((kt*8+nt)*64+lane)*8 + j] = W[(kt*32+(lane>>4)*8+j)*128 + nt*16+(lane&15)]
#define FTOT 180224
struct P8 { const u16* w[8]; };

__global__ __launch_bounds__(256) void make_frag_all(P8 ws, u16* __restrict__ fbase) {
    static const int foff[9] = { 0, 32768, 49152, 65536, 98304, 114688, 131072, 163840, 180224 };
    int i = blockIdx.x * 256 + threadIdx.x;
    if (i >= FTOT) return;
    int t = 0;
#pragma unroll 1
    while (i >= foff[t + 1]) ++t;
    int j = i - foff[t];
    int jj = j & 7, lane = (j >> 3) & 63, nt = (j >> 9) & 7, kt = j >> 12;
    int k = kt * 32 + ((lane >> 4) * 8) + jj;
    int n = nt * 16 + (lane & 15);
    fbase[i] = ws.w[t][k * 128 + n];
}

// ---------------- CSR build: count -> multiblock scan -> cursor scatter -----
__global__ void count2_kernel(const int* __restrict__ eu, const int* __restrict__ ed,
                              int* __restrict__ cu, int* __restrict__ cd) {
    int e = blockIdx.x * 256 + threadIdx.x;
    if (e < EE) atomicAdd(&cu[eu[EE + e]], 1);
    else { e -= EE; if (e < EE) atomicAdd(&cd[ed[EE + e]], 1); }
}

struct SP { const int* cnt[2]; int* cur[2]; int* bsum[2]; };

__global__ __launch_bounds__(256) void scan1_kernel(SP p) {
    int half = blockIdx.x / NBLK;
    int b = blockIdx.x - half * NBLK;
    int t = threadIdx.x;
    int i = b * 256 + t;
    __shared__ int buf[256];
    int v = (i < NN) ? p.cnt[half][i] : 0;
    buf[t] = v;
    __syncthreads();
    for (int s = 1; s < 256; s <<= 1) {
        int x = (t >= s) ? buf[t - s] : 0;
        __syncthreads();
        buf[t] += x;
        __syncthreads();
    }
    if (i < NN) p.cur[half][i] = buf[t] - v;   // exclusive within block
    if (t == 255) p.bsum[half][b] = buf[255];
}

__global__ __launch_bounds__(256) void scan2_kernel(int* __restrict__ bu, int* __restrict__ bd) {
    __shared__ int buf[2][128];
    int half = threadIdx.x >> 7, t = threadIdx.x & 127;
    int* bs = half ? bd : bu;
    int v = (t < NBLK) ? bs[t] : 0;
    buf[half][t] = v;
    __syncthreads();
    for (int s = 1; s < 128; s <<= 1) {
        int x = (t >= s) ? buf[half][t - s] : 0;
        __syncthreads();
        buf[half][t] += x;
        __syncthreads();
    }
    if (t < NBLK) bs[t] = buf[half][t] - v;    // exclusive block offsets
}

__global__ void scan3_kernel(int* __restrict__ cu, const int* __restrict__ bu,
                             int* __restrict__ cd, const int* __restrict__ bd) {
    int i = blockIdx.x * 256 + threadIdx.x;
    if (i < NN) cu[i] += bu[i >> 8];
    else { i -= NN; if (i < NN) cd[i] += bd[i >> 8]; }
}

__global__ void scatter2_kernel(const int* __restrict__ eu, const int* __restrict__ ed,
                                int* __restrict__ cu, int* __restrict__ cd,
                                int* __restrict__ su, int* __restrict__ sd) {
    int e = blockIdx.x * 256 + threadIdx.x;
    if (e < EE) { int p = atomicAdd(&cu[eu[EE + e]], 1); su[p] = e; }
    else { e -= EE; if (e < EE) { int p = atomicAdd(&cd[ed[EE + e]], 1); sd[p] = e; } }
}

// ---------------- edge kernel: 512 threads, 8 waves, 1 n-tile/wave ----------
struct EP {
    const int* eidx; const int* es; const u16* deg;
    const u16* fW1; const u16* w1last; const u16* bias1;
    const u16* fW2; const u16* bias2;
    const u16* fP1; const u16* biasp1;
    const u16* wp2; const u16* biasp2;
};

__global__ __launch_bounds__(512, 8) void edge_kernel(
    const u16* __restrict__ feat, const u16* __restrict__ posit,
    EP up, EP dn,
    float* __restrict__ msg_acc, float* __restrict__ pos_acc)
{
    const int tid = threadIdx.x;
    const int lane = tid & 63;
    const int wv = tid >> 6;              // 0..7 = n-tile
    const int half = blockIdx.x / (BB * EBLK);
    const int rem = blockIdx.x - half * (BB * EBLK);
    const int bb = rem / EBLK;                 // batch
    const int s0 = (rem - bb * EBLK) * 64;     // slot base
    const EP P = half ? dn : up;

    __shared__ u16 sX[64][136];   // h_src -> msg-hidden -> pos-hidden
    __shared__ u16 sY[64][136];   // h_dst -> messages
    __shared__ float sRel[64][3];
    __shared__ float sDist[64];
    __shared__ float sInv[64];
    __shared__ int sSrc[64], sDst[64];

    if (tid < 64) {
        int e = P.es[s0 + tid];
        int s = P.eidx[e];
        int d = P.eidx[EE + e];
        sSrc[tid] = s; sDst[tid] = d;
        sInv[tid] = 1.f / fmaxf(bf2f(P.deg[d]), 1.f);
        const u16* ps = posit + ((size_t)bb * NN + s) * 3;
        const u16* pd = posit + ((size_t)bb * NN + d) * 3;
        float dx = bf2f(ps[0]) - bf2f(pd[0]);
        float dy = bf2f(ps[1]) - bf2f(pd[1]);
        float dz = bf2f(ps[2]) - bf2f(pd[2]);
        sRel[tid][0] = dx; sRel[tid][1] = dy; sRel[tid][2] = dz;
        sDist[tid] = sqrtf(dx * dx + dy * dy + dz * dz);
    }
    __syncthreads();   // B0

    // gather h_src -> sX, h_dst -> sY (8 threads/row, 32B each)
    {
        const int r = tid >> 3, part = tid & 7;
        const uint4* fs = (const uint4*)(feat + ((size_t)bb * NN + sSrc[r]) * HH);
        const uint4* fd = (const uint4*)(feat + ((size_t)bb * NN + sDst[r]) * HH);
        uint4* as = (uint4*)&sX[r][part * 16];
        uint4* ad = (uint4*)&sY[r][part * 16];
#pragma unroll
        for (int i = 0; i < 2; ++i) { as[i] = fs[part * 2 + i]; ad[i] = fd[part * 2 + i]; }
    }
    __syncthreads();   // B1

    const int nt = wv;
    const int mrow = lane & 15;
    const int kq = (lane >> 4) * 8;
    const int crow = (lane >> 4) * 4;
    const int ccol = lane & 15;
    const int col = nt * 16 + ccol;

    f32x4 acc[4];
#pragma unroll
    for (int mt = 0; mt < 4; ++mt) acc[mt] = (f32x4){0.f, 0.f, 0.f, 0.f};

    // ----- msg layer 1 : [h_src | h_dst] @ W1[0:256]  (K=256) -----
#pragma unroll
    for (int kt = 0; kt < 8; ++kt) {
        const u16* Xb = (kt < 4) ? &sX[0][0] : &sY[0][0];
        const int kk = (kt & 3) * 32 + kq;
        bf16x8 bw = *(const bf16x8*)(P.fW1 + (size_t)(((kt * 8 + nt) * 64 + lane) * 8));
#pragma unroll
        for (int mt = 0; mt < 4; ++mt) {
            bf16x8 a = *(const bf16x8*)(Xb + (mt * 16 + mrow) * 136 + kk);
            acc[mt] = MFMA(a, bw, acc[mt]);
        }
    }
    __syncthreads();   // B2: all L1 reads of sX/sY done

    // epilogue: + dist*W1[256] + b1, silu -> sX
    {
        const float wl = bf2f(P.w1last[col]);
        const float bb2 = bf2f(P.bias1[col]);
#pragma unroll
        for (int mt = 0; mt < 4; ++mt) {
#pragma unroll
            for (int r = 0; r < 4; ++r) {
                const int row = mt * 16 + crow + r;
                float z = fmaf(sDist[row], wl, acc[mt][r]) + bb2;
                sX[row][col] = f2bf(silu_f(z));
            }
        }
    }
    __syncthreads();   // B3

    // ----- msg layer 2 : sX @ W2 + b2 = messages -> sY (K=128) -----
#pragma unroll
    for (int mt = 0; mt < 4; ++mt) acc[mt] = (f32x4){0.f, 0.f, 0.f, 0.f};
#pragma unroll
    for (int kt = 0; kt < 4; ++kt) {
        const int kk = kt * 32 + kq;
        bf16x8 bw = *(const bf16x8*)(P.fW2 + (size_t)(((kt * 8 + nt) * 64 + lane) * 8));
#pragma unroll
        for (int mt = 0; mt < 4; ++mt) {
            bf16x8 a = *(const bf16x8*)(&sX[0][0] + (mt * 16 + mrow) * 136 + kk);
            acc[mt] = MFMA(a, bw, acc[mt]);
        }
    }
    {
        const float bb2 = bf2f(P.bias2[col]);
#pragma unroll
        for (int mt = 0; mt < 4; ++mt) {
#pragma unroll
            for (int r = 0; r < 4; ++r) {
                const int row = mt * 16 + crow + r;
                sY[row][col] = f2bf(acc[mt][r] + bb2);
            }
        }
    }
    __syncthreads();   // B4: messages visible; all L2 reads of sX done

    // ----- pos layer 1 : silu(messages @ P1 + bp1) -> sX (K=128) -----
#pragma unroll
    for (int mt = 0; mt < 4; ++mt) acc[mt] = (f32x4){0.f, 0.f, 0.f, 0.f};
#pragma unroll
    for (int kt = 0; kt < 4; ++kt) {
        const int kk = kt * 32 + kq;
        bf16x8 bw = *(const bf16x8*)(P.fP1 + (size_t)(((kt * 8 + nt) * 64 + lane) * 8));
#pragma unroll
        for (int mt = 0; mt < 4; ++mt) {
            bf16x8 a = *(const bf16x8*)(&sY[0][0] + (mt * 16 + mrow) * 136 + kk);
            acc[mt] = MFMA(a, bw, acc[mt]);
        }
    }

    // segment-reduced scatter of messages (rows sorted by dst):
    // 512 threads = 128 cols x 4 row-spans of 16
    {
        const int scol = tid & 127;
        const int r0 = (tid >> 7) * 16;
        float accv = 0.f;
        int dprev = sDst[r0];
        float invprev = sInv[r0];
#pragma unroll 1
        for (int r = r0; r < r0 + 16; ++r) {
            int dcur = sDst[r];
            if (dcur != dprev) {
                unsafeAtomicAdd(&msg_acc[((size_t)bb * NN + dprev) * HH + scol], accv * invprev);
                accv = 0.f; dprev = dcur; invprev = sInv[r];
            }
            accv += bf2f(sY[r][scol]);
        }
        unsafeAtomicAdd(&msg_acc[((size_t)bb * NN + dprev) * HH + scol], accv * invprev);
    }

    // pos1 epilogue -> sX
    {
        const float bb2 = bf2f(P.biasp1[col]);
#pragma unroll
        for (int mt = 0; mt < 4; ++mt) {
#pragma unroll
            for (int r = 0; r < 4; ++r) {
                const int row = mt * 16 + crow + r;
                sX[row][col] = f2bf(silu_f(acc[mt][r] + bb2));
            }
        }
    }
    __syncthreads();   // B5

    // ----- pos layer 2 : tanh(hidden @ p2 + bp2) ; scatter wgt*rel_pos -----
    {
        const int r = tid >> 3, q = tid & 7;
        const unsigned int* t32 = (const unsigned int*)&sX[r][q * 16];
        const unsigned int* w32 = (const unsigned int*)(P.wp2 + q * 16);
        float p = 0.f;
#pragma unroll
        for (int k = 0; k < 8; ++k) {
            unsigned int a = t32[k], b = w32[k];
            union { unsigned int i; float f; } al, ah, bl, bh;
            al.i = a << 16; ah.i = a & 0xffff0000u;
            bl.i = b << 16; bh.i = b & 0xffff0000u;
            p = fmaf(al.f, bl.f, p);
            p = fmaf(ah.f, bh.f, p);
        }
        p += __shfl_xor(p, 1);
        p += __shfl_xor(p, 2);
        p += __shfl_xor(p, 4);
        if (q == 0) {
            float wgt = tanhf(p + bf2f(P.biasp2[0]));
            const size_t pb = ((size_t)bb * NN + sDst[r]) * 3;
            unsafeAtomicAdd(&pos_acc[pb + 0], wgt * sRel[r][0]);
            unsafeAtomicAdd(&pos_acc[pb + 1], wgt * sRel[r][1]);
            unsafeAtomicAdd(&pos_acc[pb + 2], wgt * sRel[r][2]);
        }
    }
}

__global__ __launch_bounds__(256) void update_kernel(
    const u16* __restrict__ feat, const void* __restrict__ rawfeat,
    const float* __restrict__ magg,
    const u16* __restrict__ fU1, const u16* __restrict__ bu1,
    const u16* __restrict__ fU2, const u16* __restrict__ bu2,
    void* __restrict__ outp, const int* __restrict__ flag)
{
    const int tid = threadIdx.x;
    const int lane = tid & 63;
    const int wv = tid >> 6;
    const int row0 = blockIdx.x * 64;   // node-instance rows
    const int isf = *flag;

    __shared__ u16 sA[64][136];   // features (bf16)
    __shared__ u16 sB[64][136];   // msg_acc -> hidden (reused)

    {
        const uint4* src = (const uint4*)(feat + (size_t)row0 * HH);
        for (int i = tid; i < 1024; i += 256) {
            int r = i >> 4, c = i & 15;
            *(uint4*)&sA[r][c * 8] = src[i];
        }
        const float4* am = (const float4*)(magg) + (size_t)row0 * 32;
        for (int i = tid; i < 2048; i += 256) {
            int r = i >> 5;
            float4 v = am[i];
            int c = (i & 31) * 4;
            sB[r][c + 0] = f2bf(v.x);
            sB[r][c + 1] = f2bf(v.y);
            sB[r][c + 2] = f2bf(v.z);
            sB[r][c + 3] = f2bf(v.w);
        }
    }
    __syncthreads();

    const int nt0 = wv * 2;
    const int mrow = lane & 15;
    const int kq = (lane >> 4) * 8;
    const int crow = (lane >> 4) * 4;
    const int ccol = lane & 15;

    f32x4 acc[4][2];
#pragma unroll
    for (int mt = 0; mt < 4; ++mt) {
        acc[mt][0] = (f32x4){0.f, 0.f, 0.f, 0.f};
        acc[mt][1] = (f32x4){0.f, 0.f, 0.f, 0.f};
    }
    // layer 1: [features | msg_acc] @ w_upd1 (K=256), silu
#pragma unroll
    for (int kt = 0; kt < 8; ++kt) {
        const u16* Xb = (kt < 4) ? &sA[0][0] : &sB[0][0];
        const int kk = (kt & 3) * 32 + kq;
        bf16x8 bw0 = *(const bf16x8*)(fU1 + (size_t)(((kt * 8 + nt0) * 64 + lane) * 8));
        bf16x8 bw1 = *(const bf16x8*)(fU1 + (size_t)(((kt * 8 + nt0 + 1) * 64 + lane) * 8));
#pragma unroll
        for (int mt = 0; mt < 4; ++mt) {
            bf16x8 a = *(const bf16x8*)(Xb + (mt * 16 + mrow) * 136 + kk);
            acc[mt][0] = MFMA(a, bw0, acc[mt][0]);
            acc[mt][1] = MFMA(a, bw1, acc[mt][1]);
        }
    }
    __syncthreads();   // all L1 reads of sB done

    // hidden -> sB (reuse)
#pragma unroll
    for (int mt = 0; mt < 4; ++mt) {
#pragma unroll
        for (int n2 = 0; n2 < 2; ++n2) {
            const int col = (nt0 + n2) * 16 + ccol;
            const float bb = bf2f(bu1[col]);
#pragma unroll
            for (int r = 0; r < 4; ++r) {
                const int row = mt * 16 + crow + r;
                sB[row][col] = f2bf(silu_f(acc[mt][n2][r] + bb));
            }
        }
    }
    __syncthreads();

    // layer 2 + residual -> out
#pragma unroll
    for (int mt = 0; mt < 4; ++mt) {
        acc[mt][0] = (f32x4){0.f, 0.f, 0.f, 0.f};
        acc[mt][1] = (f32x4){0.f, 0.f, 0.f, 0.f};
    }
#pragma unroll
    for (int kt = 0; kt < 4; ++kt) {
        const int kk = kt * 32 + kq;
        bf16x8 bw0 = *(const bf16x8*)(fU2 + (size_t)(((kt * 8 + nt0) * 64 + lane) * 8));
        bf16x8 bw1 = *(const bf16x8*)(fU2 + (size_t)(((kt * 8 + nt0 + 1) * 64 + lane) * 8));
#pragma unroll
        for (int mt = 0; mt < 4; ++mt) {
            bf16x8 a = *(const bf16x8*)(&sB[0][0] + (mt * 16 + mrow) * 136 + kk);
            acc[mt][0] = MFMA(a, bw0, acc[mt][0]);
            acc[mt][1] = MFMA(a, bw1, acc[mt][1]);
        }
    }
#pragma unroll
    for (int mt = 0; mt < 4; ++mt) {
#pragma unroll
        for (int n2 = 0; n2 < 2; ++n2) {
            const int col = (nt0 + n2) * 16 + ccol;
            const float bb = bf2f(bu2[col]);
#pragma unroll
            for (int r = 0; r < 4; ++r) {
                const int row = mt * 16 + crow + r;
                const size_t idx = (size_t)(row0 + row) * HH + col;
                if (isf) {
                    float base = ((const float*)rawfeat)[idx];
                    ((float*)outp)[idx] = acc[mt][n2][r] + bb + base;
                } else {
                    float base = bf2f(sA[row][col]);
                    ((u16*)outp)[idx] = f2bf(acc[mt][n2][r] + bb + base);
                }
            }
        }
    }
}

__global__ void pos_out_kernel(const void* __restrict__ rawpos, const u16* __restrict__ cpos,
                               const float* __restrict__ pacc, void* __restrict__ outp,
                               const int* __restrict__ flag)
{
    int i = blockIdx.x * 256 + threadIdx.x;
    if (i >= BB * NN * 3) return;
    if (*flag) {
        float base = ((const float*)rawpos)[i];
        ((float*)outp)[5120000 + i] = base + 0.5f * pacc[i];
    } else {
        float base = bf2f(cpos[i]);
        ((u16*)outp)[5120000 + i] = f2bf(base + 0.5f * pacc[i]);
    }
}

extern "C" void kernel_launch(void* const* d_in, const int* in_sizes, int n_in,
                              void* d_out, int out_size, void* d_ws, size_t ws_size,
                              hipStream_t stream)
{
    // workspace layout (bytes): same as round 5
    float* msg_acc = (float*)d_ws;
    float* pos_acc = (float*)((char*)d_ws + 20480000);
    int*   cnt_up  = (int*)((char*)d_ws + 20960000);
    int*   cnt_dn  = (int*)((char*)d_ws + 21040000);
    const size_t ZERO_BYTES = 21120000;
    int*   cur_up  = (int*)((char*)d_ws + 21120000);
    int*   cur_dn  = (int*)((char*)d_ws + 21200000);
    int*   bsum_up = (int*)((char*)d_ws + 21280000);
    int*   bsum_dn = (int*)((char*)d_ws + 21280400);
    int*   es_up   = (int*)((char*)d_ws + 21280800);
    int*   es_dn   = (int*)((char*)d_ws + 22080800);
    u16*   fbase   = (u16*)((char*)d_ws + 22880800);
    u16*   canon   = (u16*)((char*)d_ws + 23241248);
    int*   flag    = (int*)((char*)d_ws + 34164800);
    if (ws_size < 34164804ULL) return;

    u16* f_m1u = fbase;              // 32768 (K=256)
    u16* f_m2u = fbase + 32768;      // 16384 (K=128)
    u16* f_p1u = fbase + 49152;      // 16384
    u16* f_m1d = fbase + 65536;      // 32768
    u16* f_m2d = fbase + 98304;      // 16384
    u16* f_p1d = fbase + 114688;     // 16384
    u16* f_u1  = fbase + 131072;     // 32768
    u16* f_u2  = fbase + 163840;     // 16384

    // canonical tensor pointers
    u16* cfeat = canon;
    u16* cpos  = canon + 5120000;
    u16* cdgu  = canon + 5240000;
    u16* cdgd  = canon + 5260000;
    u16* cm1u  = canon + 5280000;
    u16* cbm1u = canon + 5312896;
    u16* cm2u  = canon + 5313024;
    u16* cbm2u = canon + 5329408;
    u16* cp1u  = canon + 5329536;
    u16* cbp1u = canon + 5345920;
    u16* cp2u  = canon + 5346048;
    u16* cbp2u = canon + 5346176;
    u16* cm1d  = canon + 5346184;
    u16* cbm1d = canon + 5379080;
    u16* cm2d  = canon + 5379208;
    u16* cbm2d = canon + 5395592;
    u16* cp1d  = canon + 5395720;
    u16* cbp1d = canon + 5412104;
    u16* cp2d  = canon + 5412232;
    u16* cbp2d = canon + 5412360;
    u16* cu1   = canon + 5412368;
    u16* cbu1  = canon + 5445136;
    u16* cu2   = canon + 5445264;
    u16* cbu2  = canon + 5461648;

    hipMemsetAsync(d_ws, 0, ZERO_BYTES, stream);

    detect_kernel<<<1, 256, 0, stream>>>((const u16*)d_in[0], flag);

    P24 ptrs;
    ptrs.p[0] = d_in[0];  ptrs.p[1] = d_in[1];  ptrs.p[2] = d_in[4];  ptrs.p[3] = d_in[5];
    ptrs.p[4] = d_in[6];  ptrs.p[5] = d_in[7];  ptrs.p[6] = d_in[8];  ptrs.p[7] = d_in[9];
    ptrs.p[8] = d_in[10]; ptrs.p[9] = d_in[11]; ptrs.p[10] = d_in[12]; ptrs.p[11] = d_in[13];
    ptrs.p[12] = d_in[14]; ptrs.p[13] = d_in[15]; ptrs.p[14] = d_in[16]; ptrs.p[15] = d_in[17];
    ptrs.p[16] = d_in[18]; ptrs.p[17] = d_in[19]; ptrs.p[18] = d_in[20]; ptrs.p[19] = d_in[21];
    ptrs.p[20] = d_in[22]; ptrs.p[21] = d_in[23]; ptrs.p[22] = d_in[24]; ptrs.p[23] = d_in[25];
    canon_kernel<<<(CTOT + 255) / 256, 256, 0, stream>>>(ptrs, flag, canon);

    P8 wsf;
    wsf.w[0] = cm1u; wsf.w[1] = cm2u; wsf.w[2] = cp1u; wsf.w[3] = cm1d;
    wsf.w[4] = cm2d; wsf.w[5] = cp1d; wsf.w[6] = cu1;  wsf.w[7] = cu2;
    make_frag_all<<<(FTOT + 255) / 256, 256, 0, stream>>>(wsf, fbase);

    const int* ei_up = (const int*)d_in[2];
    const int* ei_dn = (const int*)d_in[3];

    // CSR build: count -> multiblock scan -> cursor scatter (both neighborhoods)
    count2_kernel<<<(2 * EE + 255) / 256, 256, 0, stream>>>(ei_up, ei_dn, cnt_up, cnt_dn);
    SP sp;
    sp.cnt[0] = cnt_up; sp.cnt[1] = cnt_dn;
    sp.cur[0] = cur_up; sp.cur[1] = cur_dn;
    sp.bsum[0] = bsum_up; sp.bsum[1] = bsum_dn;
    scan1_kernel<<<2 * NBLK, 256, 0, stream>>>(sp);
    scan2_kernel<<<1, 256, 0, stream>>>(bsum_up, bsum_dn);
    scan3_kernel<<<(2 * NN + 255) / 256, 256, 0, stream>>>(cur_up, bsum_up, cur_dn, bsum_dn);
    scatter2_kernel<<<(2 * EE + 255) / 256, 256, 0, stream>>>(ei_up, ei_dn, cur_up, cur_dn,
                                                              es_up, es_dn);

    EP up, dn;
    up.eidx = ei_up; up.es = es_up; up.deg = cdgu;
    up.fW1 = f_m1u; up.w1last = cm1u + 256 * 128; up.bias1 = cbm1u;
    up.fW2 = f_m2u; up.bias2 = cbm2u;
    up.fP1 = f_p1u; up.biasp1 = cbp1u;
    up.wp2 = cp2u;  up.biasp2 = cbp2u;
    dn.eidx = ei_dn; dn.es = es_dn; dn.deg = cdgd;
    dn.fW1 = f_m1d; dn.w1last = cm1d + 256 * 128; dn.bias1 = cbm1d;
    dn.fW2 = f_m2d; dn.bias2 = cbm2d;
    dn.fP1 = f_p1d; dn.biasp1 = cbp1d;
    dn.wp2 = cp2d;  dn.biasp2 = cbp2d;

    edge_kernel<<<2 * BB * EBLK, 512, 0, stream>>>(cfeat, cpos, up, dn, msg_acc, pos_acc);

    update_kernel<<<625, 256, 0, stream>>>(
        cfeat, d_in[0], msg_acc,
        f_u1, cbu1, f_u2, cbu2, d_out, flag);

    pos_out_kernel<<<469, 256, 0, stream>>>(d_in[1], cpos, pos_acc, d_out, flag);
}